// Round 5
// baseline (863.360 us; speedup 1.0000x reference)
//
#include <hip/hip_runtime.h>
#include <hip/hip_bf16.h>

// ---------------------------------------------------------------------------
// GAT (2 GATConv + 5-layer MLP), MI355X.
// R4: bf16 hi/lo planes end-to-end, split-bf16 MFMA (3 terms), fused el/er.
// R5: head-major GEMM output [3][N][128]; softmax fused into agg
//     (wave per (node,head), online-softmax, shfl broadcast); mden deleted.
// ---------------------------------------------------------------------------

typedef __attribute__((ext_vector_type(8))) short short8;   // 8 bf16 = 4 VGPR
typedef __attribute__((ext_vector_type(4))) float float4v;  // MFMA C/D

__device__ inline short f2bf(float x) {
    union { float f; unsigned u; } v; v.f = x;
    unsigned r = v.u + 0x7FFFu + ((v.u >> 16) & 1u);   // RNE
    return (short)(r >> 16);
}
__device__ inline float bf2f(short b) {
    union { float f; unsigned u; } v;
    v.u = ((unsigned)(unsigned short)b) << 16;
    return v.f;
}
__device__ inline short8 zero8() { short8 z = {0,0,0,0,0,0,0,0}; return z; }

#define BM 128
#define BN 128
#define BK 32
#define LSTR 40   // LDS row stride in shorts (80 B, 16B-aligned, breaks pow2)

// ---------------------------------------------------------------------------
__global__ void conv_split(const float* __restrict__ x, short* __restrict__ hi,
                           short* __restrict__ lo, int n4)
{
    int i = blockIdx.x * blockDim.x + threadIdx.x;
    if (i >= n4) return;
    float4 v = *(const float4*)(x + (size_t)i * 4);
    float xs[4] = {v.x, v.y, v.z, v.w};
    short hs[4], ls[4];
    #pragma unroll
    for (int j = 0; j < 4; ++j) {
        hs[j] = f2bf(xs[j]);
        ls[j] = f2bf(xs[j] - bf2f(hs[j]));
    }
    *(uint2*)(hi + (size_t)i * 4) = *(uint2*)hs;
    *(uint2*)(lo + (size_t)i * 4) = *(uint2*)ls;
}

// Weight: fp32 [K][Nc] -> transposed bf16 hi/lo planes [Nc][K].
__global__ void convw_t(const float* __restrict__ w, short* __restrict__ th,
                        short* __restrict__ tl, int K, int Nc)
{
    int i = blockIdx.x * blockDim.x + threadIdx.x;
    if (i >= K * Nc) return;
    int k = i / Nc, c = i - k * Nc;
    float v = w[i];
    short h = f2bf(v);
    th[(size_t)c * K + k] = h;
    tl[(size_t)c * K + k] = f2bf(v - bf2f(h));
}

// ---------------------------------------------------------------------------
// GEMM: C[M x Nc] = A @ W. A hi/lo planes [M][128], W^T hi/lo planes [Nc][128].
// flags: 1 bias, 2 lrelu(0.01), 4 fused el/er (head = blockIdx.x; Nc=384),
//        8 fp32 C, 16 hi plane, 32 lo plane, 64 head-major C [(head*M+r)*128+c']
__global__ __launch_bounds__(256) void gemm_mfma(
    const short* __restrict__ Ahi, const short* __restrict__ Alo,
    const short* __restrict__ Bth, const short* __restrict__ Btl,
    const float* __restrict__ bias,
    float* __restrict__ Cf, short* __restrict__ Chi, short* __restrict__ Clo,
    float* __restrict__ el, float* __restrict__ er,
    const float* __restrict__ al, const float* __restrict__ ar,
    int M, int Nc, int flags)
{
    __shared__ short Ah[BM * LSTR], Al_[BM * LSTR];
    __shared__ short Bh[BN * LSTR], Bl_[BN * LSTR];

    int tid = threadIdx.x, lane = tid & 63, wave = tid >> 6;
    int l15 = lane & 15, q = lane >> 4;
    int rowBase = blockIdx.y * BM, colBase = blockIdx.x * BN;

    float4v acc[2][8];
    #pragma unroll
    for (int mt = 0; mt < 2; ++mt)
        #pragma unroll
        for (int nt = 0; nt < 8; ++nt)
            acc[mt][nt] = (float4v){0.f, 0.f, 0.f, 0.f};

    for (int k0 = 0; k0 < 128; k0 += BK) {
        #pragma unroll
        for (int s = 0; s < 2; ++s) {
            int c = tid + s * 256;
            int r = c >> 2, kq = (c & 3) * 8;
            int gr = rowBase + r;
            short8 vh = zero8(), vl = zero8();
            if (gr < M) {
                vh = *(const short8*)(Ahi + (size_t)gr * 128 + k0 + kq);
                vl = *(const short8*)(Alo + (size_t)gr * 128 + k0 + kq);
            }
            *(short8*)&Ah[r * LSTR + kq]  = vh;
            *(short8*)&Al_[r * LSTR + kq] = vl;
            int gc = colBase + r;
            short8 wh = zero8(), wl = zero8();
            if (gc < Nc) {
                wh = *(const short8*)(Bth + (size_t)gc * 128 + k0 + kq);
                wl = *(const short8*)(Btl + (size_t)gc * 128 + k0 + kq);
            }
            *(short8*)&Bh[r * LSTR + kq]  = wh;
            *(short8*)&Bl_[r * LSTR + kq] = wl;
        }
        __syncthreads();

        short8 aH[2], aL2[2];
        #pragma unroll
        for (int mt = 0; mt < 2; ++mt) {
            int off = (wave * 32 + mt * 16 + l15) * LSTR + q * 8;
            aH[mt]  = *(short8*)&Ah[off];
            aL2[mt] = *(short8*)&Al_[off];
        }
        #pragma unroll
        for (int nt = 0; nt < 8; ++nt) {
            int off = (nt * 16 + l15) * LSTR + q * 8;
            short8 bH = *(short8*)&Bh[off];
            short8 bL = *(short8*)&Bl_[off];
            #pragma unroll
            for (int mt = 0; mt < 2; ++mt) {
                acc[mt][nt] = __builtin_amdgcn_mfma_f32_16x16x32_bf16(aH[mt], bH, acc[mt][nt], 0, 0, 0);
                acc[mt][nt] = __builtin_amdgcn_mfma_f32_16x16x32_bf16(aH[mt], bL, acc[mt][nt], 0, 0, 0);
                acc[mt][nt] = __builtin_amdgcn_mfma_f32_16x16x32_bf16(aL2[mt], bH, acc[mt][nt], 0, 0, 0);
            }
        }
        __syncthreads();
    }

    // ---- fused el/er (GAT)
    if (flags & 4) {
        const float* alh = al + colBase;
        const float* arh = ar + colBase;
        float pel[2][4] = {}, per_[2][4] = {};
        #pragma unroll
        for (int nt = 0; nt < 8; ++nt) {
            float av = alh[nt * 16 + l15];
            float rv = arh[nt * 16 + l15];
            #pragma unroll
            for (int mt = 0; mt < 2; ++mt)
                #pragma unroll
                for (int i = 0; i < 4; ++i) {
                    pel[mt][i]  += acc[mt][nt][i] * av;
                    per_[mt][i] += acc[mt][nt][i] * rv;
                }
        }
        #pragma unroll
        for (int mask = 1; mask < 16; mask <<= 1)
            #pragma unroll
            for (int mt = 0; mt < 2; ++mt)
                #pragma unroll
                for (int i = 0; i < 4; ++i) {
                    pel[mt][i]  += __shfl_xor(pel[mt][i], mask);
                    per_[mt][i] += __shfl_xor(per_[mt][i], mask);
                }
        if (l15 == 0) {
            #pragma unroll
            for (int mt = 0; mt < 2; ++mt)
                #pragma unroll
                for (int i = 0; i < 4; ++i) {
                    int r = rowBase + wave * 32 + mt * 16 + q * 4 + i;
                    if (r < M) {
                        el[r * 3 + blockIdx.x] = pel[mt][i];
                        er[r * 3 + blockIdx.x] = per_[mt][i];
                    }
                }
        }
    }

    // ---- C write
    #pragma unroll
    for (int mt = 0; mt < 2; ++mt) {
        #pragma unroll
        for (int nt = 0; nt < 8; ++nt) {
            int c = colBase + nt * 16 + l15;
            if (c >= Nc) continue;
            float bv = (flags & 1) ? bias[c] : 0.f;
            #pragma unroll
            for (int i = 0; i < 4; ++i) {
                int r = rowBase + wave * 32 + mt * 16 + q * 4 + i;
                if (r >= M) continue;
                float v = acc[mt][nt][i] + bv;
                if (flags & 2) v = (v < 0.f) ? 0.01f * v : v;
                size_t idx = (flags & 64)
                    ? (((size_t)blockIdx.x * M + r) << 7) + (size_t)(c - colBase)
                    : (size_t)r * Nc + c;
                if (flags & 8)  Cf[idx] = v;
                if (flags & 16) {
                    short hh = f2bf(v);
                    Chi[idx] = hh;
                    if (flags & 32) Clo[idx] = f2bf(v - bf2f(hh));
                }
            }
        }
    }
}

// ---------------------------------------------------------------------------
// CSR build
__global__ void hist_kernel(const int* __restrict__ dst, int* __restrict__ cnt, int E)
{
    int e = blockIdx.x * blockDim.x + threadIdx.x;
    if (e < E) atomicAdd(&cnt[dst[e]], 1);
}

__global__ __launch_bounds__(1024) void scan_block(const int* __restrict__ cnt,
                                                   int* __restrict__ off,
                                                   int* __restrict__ bsum, int n)
{
    __shared__ int tmp[1024];
    int tid = threadIdx.x;
    int i = blockIdx.x * 1024 + tid;
    int v = (i < n) ? cnt[i] : 0;
    tmp[tid] = v;
    __syncthreads();
    for (int s = 1; s < 1024; s <<= 1) {
        int t = (tid >= s) ? tmp[tid - s] : 0;
        __syncthreads();
        tmp[tid] += t;
        __syncthreads();
    }
    if (i < n) off[i] = tmp[tid] - v;
    if (tid == 1023) bsum[blockIdx.x] = tmp[1023];
}

__global__ __launch_bounds__(256) void scan_tops(int* __restrict__ bsum, int nb)
{
    __shared__ int tmp[256];
    int tid = threadIdx.x;
    int v = (tid < nb) ? bsum[tid] : 0;
    tmp[tid] = v;
    __syncthreads();
    for (int s = 1; s < 256; s <<= 1) {
        int t = (tid >= s) ? tmp[tid - s] : 0;
        __syncthreads();
        tmp[tid] += t;
        __syncthreads();
    }
    if (tid < nb) bsum[tid] = tmp[tid] - v;
    if (tid == 0) bsum[nb] = tmp[255];
}

__global__ void scan_add(int* __restrict__ off, const int* __restrict__ bsum,
                         int n, int nb)
{
    int i = blockIdx.x * blockDim.x + threadIdx.x;
    if (i < n) off[i] += bsum[i >> 10];
    if (i == 0) off[n] = bsum[nb];
}

__global__ void scatter_kernel(const int* __restrict__ src, const int* __restrict__ dst,
                               const int* __restrict__ off, int* __restrict__ pcnt,
                               int* __restrict__ csrc, int E)
{
    int e = blockIdx.x * blockDim.x + threadIdx.x;
    if (e < E) {
        int d = dst[e];
        int p = atomicAdd(&pcnt[d], 1);
        csrc[off[d] + p] = src[e];
    }
}

// ---------------------------------------------------------------------------
// Fused edge-softmax + weighted gather + bias + lrelu + head-mean.
// h: [3][N][128] bf16-hi head-major. One wave per (node, head);
// block = 384 threads = 2 nodes x 3 head-waves. Online softmax over 64-edge
// chunks (lanes hold edges); per-edge weight broadcast by shfl.
__global__ __launch_bounds__(384) void gat_agg(
    const short* __restrict__ h, const float* __restrict__ el,
    const float* __restrict__ er, const int* __restrict__ off,
    const int* __restrict__ csrc, const float* __restrict__ bias,
    short* __restrict__ outH, short* __restrict__ outL, int N)
{
    int tid = threadIdx.x;
    int wave = tid >> 6, lane = tid & 63;
    int slot = (wave >= 3) ? 1 : 0;
    int head = wave - slot * 3;
    int n = blockIdx.x * 2 + slot;

    __shared__ float sm[2][3][128];

    if (n < N) {
        int beg = off[n], end = off[n + 1];
        int deg = end - beg;
        float erv = er[n * 3 + head];
        const short* hh = h + (size_t)head * N * 128;

        float m_run = -1e30f, den = 0.f, ax = 0.f, ay = 0.f;
        for (int base = 0; base < deg; base += 64) {
            bool act = (base + lane) < deg;
            int s = act ? csrc[beg + base + lane] : 0;
            float e = -1e30f;
            if (act) {
                e = el[s * 3 + head] + erv;
                e = (e < 0.f) ? 0.2f * e : e;
            }
            float mc = e;
            #pragma unroll
            for (int msk = 1; msk < 64; msk <<= 1)
                mc = fmaxf(mc, __shfl_xor(mc, msk));
            float mn = fmaxf(m_run, mc);
            float scale = __expf(m_run - mn);   // first chunk: exp(-inf)=0, den/acc are 0
            den *= scale; ax *= scale; ay *= scale;
            float w = act ? __expf(e - mn) : 0.f;
            float ws = w;
            #pragma unroll
            for (int msk = 1; msk < 64; msk <<= 1)
                ws += __shfl_xor(ws, msk);
            den += ws;
            int cnt = min(64, deg - base);
            for (int q2 = 0; q2 < cnt; ++q2) {
                int   sq = __shfl(s, q2);
                float wq = __shfl(w, q2);
                unsigned v = *(const unsigned*)(hh + (size_t)sq * 128 + lane * 2);
                union { unsigned u; float f; } f0, f1;
                f0.u = v << 16; f1.u = v & 0xffff0000u;
                ax += wq * f0.f;
                ay += wq * f1.f;
            }
            m_run = mn;
        }
        float r = (deg > 0) ? 1.f / (den + 1e-9f) : 0.f;
        float2 bv = *(const float2*)(bias + head * 128 + lane * 2);
        float vx = ax * r + bv.x;
        float vy = ay * r + bv.y;
        vx = (vx < 0.f) ? 0.01f * vx : vx;
        vy = (vy < 0.f) ? 0.01f * vy : vy;
        sm[slot][head][lane * 2]     = vx;
        sm[slot][head][lane * 2 + 1] = vy;
    }
    __syncthreads();
    if (head == 0 && n < N) {
        int f0 = lane * 2, f1 = lane * 2 + 1;
        float mx = (sm[slot][0][f0] + sm[slot][1][f0] + sm[slot][2][f0]) * (1.f / 3.f);
        float my = (sm[slot][0][f1] + sm[slot][1][f1] + sm[slot][2][f1]) * (1.f / 3.f);
        short hx = f2bf(mx), lx = f2bf(mx - bf2f(hx));
        short hy = f2bf(my), ly = f2bf(my - bf2f(hy));
        unsigned ph = (unsigned)(unsigned short)hx | ((unsigned)(unsigned short)hy << 16);
        unsigned pl = (unsigned)(unsigned short)lx | ((unsigned)(unsigned short)ly << 16);
        *(unsigned*)(outH + (size_t)n * 128 + f0) = ph;
        *(unsigned*)(outL + (size_t)n * 128 + f0) = pl;
    }
}

// ---------------------------------------------------------------------------
extern "C" void kernel_launch(void* const* d_in, const int* in_sizes, int n_in,
                              void* d_out, int out_size, void* d_ws, size_t ws_size,
                              hipStream_t stream)
{
    const float* in_feat = (const float*)d_in[0];
    const int*   src     = (const int*)d_in[1];
    const int*   dst     = (const int*)d_in[2];
    const float* W1  = (const float*)d_in[3];
    const float* al1 = (const float*)d_in[4];
    const float* ar1 = (const float*)d_in[5];
    const float* b1  = (const float*)d_in[6];
    const float* W2  = (const float*)d_in[7];
    const float* al2 = (const float*)d_in[8];
    const float* ar2 = (const float*)d_in[9];
    const float* b2  = (const float*)d_in[10];
    const float* lw1 = (const float*)d_in[11];
    const float* lb1 = (const float*)d_in[12];
    const float* lw2 = (const float*)d_in[13];
    const float* lb2 = (const float*)d_in[14];
    const float* lw3 = (const float*)d_in[15];
    const float* lb3 = (const float*)d_in[16];
    const float* lw4 = (const float*)d_in[17];
    const float* lb4 = (const float*)d_in[18];
    const float* lw5 = (const float*)d_in[19];
    const float* lb5 = (const float*)d_in[20];

    const int N = in_sizes[0] / 128;   // 50000
    const int E = in_sizes[1];         // 800000

    size_t o = 0;
    auto alloc = [&](size_t bytes) { size_t p = o; o = (o + bytes + 255) & ~(size_t)255; return p; };
    char* ws = (char*)d_ws;
    short* P1h = (short*)(ws + alloc((size_t)N * 128 * 2));
    short* P1l = (short*)(ws + alloc((size_t)N * 128 * 2));
    short* P2h = (short*)(ws + alloc((size_t)N * 128 * 2));
    short* P2l = (short*)(ws + alloc((size_t)N * 128 * 2));
    short* AbH = (short*)(ws + alloc((size_t)N * 384 * 2));   // head-major [3][N][128]
    float* el  = (float*)(ws + alloc((size_t)N * 3 * 4));
    float* er  = (float*)(ws + alloc((size_t)N * 3 * 4));
    int*   cnt  = (int*)(ws + alloc((size_t)N * 4));
    int*   pcnt = (int*)(ws + alloc((size_t)N * 4));
    int*   off  = (int*)(ws + alloc((size_t)(N + 1) * 4));
    int*   bsum = (int*)(ws + alloc((size_t)4096));
    int*   csrc = (int*)(ws + alloc((size_t)E * 4));
    short* w1th = (short*)(ws + alloc((size_t)384 * 128 * 2));
    short* w1tl = (short*)(ws + alloc((size_t)384 * 128 * 2));
    short* w2th = (short*)(ws + alloc((size_t)384 * 128 * 2));
    short* w2tl = (short*)(ws + alloc((size_t)384 * 128 * 2));
    short* l1th = (short*)(ws + alloc((size_t)128 * 128 * 2));
    short* l1tl = (short*)(ws + alloc((size_t)128 * 128 * 2));
    short* l2th = (short*)(ws + alloc((size_t)128 * 128 * 2));
    short* l2tl = (short*)(ws + alloc((size_t)128 * 128 * 2));
    short* l3th = (short*)(ws + alloc((size_t)128 * 128 * 2));
    short* l3tl = (short*)(ws + alloc((size_t)128 * 128 * 2));
    short* l4th = (short*)(ws + alloc((size_t)128 * 128 * 2));
    short* l4tl = (short*)(ws + alloc((size_t)128 * 128 * 2));
    short* l5th = (short*)(ws + alloc((size_t)6 * 128 * 2));
    short* l5tl = (short*)(ws + alloc((size_t)6 * 128 * 2));
    (void)ws_size;

    float* out = (float*)d_out;

    // ---- input/weight conversions
    conv_split<<<(N * 128 / 4 + 255) / 256, 256, 0, stream>>>(in_feat, P1h, P1l, N * 128 / 4);
    convw_t<<<(128 * 384 + 255) / 256, 256, 0, stream>>>(W1, w1th, w1tl, 128, 384);
    convw_t<<<(128 * 384 + 255) / 256, 256, 0, stream>>>(W2, w2th, w2tl, 128, 384);
    convw_t<<<(128 * 128 + 255) / 256, 256, 0, stream>>>(lw1, l1th, l1tl, 128, 128);
    convw_t<<<(128 * 128 + 255) / 256, 256, 0, stream>>>(lw2, l2th, l2tl, 128, 128);
    convw_t<<<(128 * 128 + 255) / 256, 256, 0, stream>>>(lw3, l3th, l3tl, 128, 128);
    convw_t<<<(128 * 128 + 255) / 256, 256, 0, stream>>>(lw4, l4th, l4tl, 128, 128);
    convw_t<<<(128 * 6 + 255) / 256, 256, 0, stream>>>(lw5, l5th, l5tl, 128, 6);

    // ---- CSR build
    hipMemsetAsync(cnt, 0, (size_t)N * 4, stream);
    hipMemsetAsync(pcnt, 0, (size_t)N * 4, stream);
    hist_kernel<<<(E + 255) / 256, 256, 0, stream>>>(dst, cnt, E);
    int nb = (N + 1023) / 1024;
    scan_block<<<nb, 1024, 0, stream>>>(cnt, off, bsum, N);
    scan_tops<<<1, 256, 0, stream>>>(bsum, nb);
    scan_add<<<(N + 255) / 256, 256, 0, stream>>>(off, bsum, N, nb);
    scatter_kernel<<<(E + 255) / 256, 256, 0, stream>>>(src, dst, off, pcnt, csrc, E);

    int RB = (N + BM - 1) / BM;
    auto gemm = [&](const short* ah, const short* alo, const short* bth, const short* btl,
                    const float* bias, float* cf, short* chi, short* clo,
                    float* elp, float* erp, const float* alp, const float* arp,
                    int Nc, int flags) {
        dim3 grid((Nc + BN - 1) / BN, RB);
        gemm_mfma<<<grid, 256, 0, stream>>>(ah, alo, bth, btl, bias, cf, chi, clo,
                                            elp, erp, alp, arp, N, Nc, flags);
    };
    int aggGrid = (N + 1) / 2;

    // ---- GAT layer 1
    gemm(P1h, P1l, w1th, w1tl, nullptr, nullptr, AbH, nullptr, el, er, al1, ar1, 384, 4 | 16 | 64);
    gat_agg<<<aggGrid, 384, 0, stream>>>(AbH, el, er, off, csrc, b1, P2h, P2l, N);

    // ---- GAT layer 2
    gemm(P2h, P2l, w2th, w2tl, nullptr, nullptr, AbH, nullptr, el, er, al2, ar2, 384, 4 | 16 | 64);
    gat_agg<<<aggGrid, 384, 0, stream>>>(AbH, el, er, off, csrc, b2, P1h, P1l, N);

    // ---- MLP head
    gemm(P1h, P1l, l1th, l1tl, lb1, nullptr, P2h, P2l, nullptr, nullptr, nullptr, nullptr, 128, 1 | 2 | 16 | 32);
    gemm(P2h, P2l, l2th, l2tl, lb2, nullptr, P1h, P1l, nullptr, nullptr, nullptr, nullptr, 128, 1 | 2 | 16 | 32);
    gemm(P1h, P1l, l3th, l3tl, lb3, nullptr, P2h, P2l, nullptr, nullptr, nullptr, nullptr, 128, 1 | 2 | 16 | 32);
    gemm(P2h, P2l, l4th, l4tl, lb4, nullptr, P1h, P1l, nullptr, nullptr, nullptr, nullptr, 128, 1 | 2 | 16 | 32);
    gemm(P1h, P1l, l5th, l5tl, lb5, out, nullptr, nullptr, nullptr, nullptr, nullptr, nullptr, 6, 1 | 8);
}

// Round 7
// 691.478 us; speedup vs baseline: 1.2486x; 1.2486x over previous
//
#include <hip/hip_runtime.h>
#include <hip/hip_bf16.h>

// ---------------------------------------------------------------------------
// GAT (2 GATConv + 5-layer MLP), MI355X.
// R4 (proven): bf16 hi/lo planes end-to-end, split-bf16 MFMA (3 terms),
//     fused el/er in GEMM epilogue, mden thread-per-(node,head),
//     agg block-per-node edge-parallel gather.
// R7: agg widened to 2 features/lane (uint bf16-pair loads, 192 threads);
//     weight conversions merged into one launch. R6's mden_wave/gat_agg
//     reverted (unexplained post-timing divergence — see journal).
// ---------------------------------------------------------------------------

typedef __attribute__((ext_vector_type(8))) short short8;   // 8 bf16 = 4 VGPR
typedef __attribute__((ext_vector_type(4))) float float4v;  // MFMA C/D

__device__ inline short f2bf(float x) {
    union { float f; unsigned u; } v; v.f = x;
    unsigned r = v.u + 0x7FFFu + ((v.u >> 16) & 1u);   // RNE
    return (short)(r >> 16);
}
__device__ inline float bf2f(short b) {
    union { float f; unsigned u; } v;
    v.u = ((unsigned)(unsigned short)b) << 16;
    return v.f;
}
__device__ inline short8 zero8() { short8 z = {0,0,0,0,0,0,0,0}; return z; }

#define BM 128
#define BN 128
#define BK 32
#define LSTR 40   // LDS row stride in shorts (80 B, 16B-aligned, breaks pow2)

// ---------------------------------------------------------------------------
__global__ void conv_split(const float* __restrict__ x, short* __restrict__ hi,
                           short* __restrict__ lo, int n4)
{
    int i = blockIdx.x * blockDim.x + threadIdx.x;
    if (i >= n4) return;
    float4 v = *(const float4*)(x + (size_t)i * 4);
    float xs[4] = {v.x, v.y, v.z, v.w};
    short hs[4], ls[4];
    #pragma unroll
    for (int j = 0; j < 4; ++j) {
        hs[j] = f2bf(xs[j]);
        ls[j] = f2bf(xs[j] - bf2f(hs[j]));
    }
    *(uint2*)(hi + (size_t)i * 4) = *(uint2*)hs;
    *(uint2*)(lo + (size_t)i * 4) = *(uint2*)ls;
}

// All 7 weight matrices: fp32 [128][Nc] -> transposed bf16 hi/lo [Nc][128].
// blockIdx.y selects the matrix.
__global__ void convw_all(
    const float* __restrict__ w1, const float* __restrict__ w2,
    const float* __restrict__ m1, const float* __restrict__ m2,
    const float* __restrict__ m3, const float* __restrict__ m4,
    const float* __restrict__ w5,
    short* __restrict__ w1h, short* __restrict__ w1l,
    short* __restrict__ w2h, short* __restrict__ w2l,
    short* __restrict__ m1h, short* __restrict__ m1l,
    short* __restrict__ m2h, short* __restrict__ m2l,
    short* __restrict__ m3h, short* __restrict__ m3l,
    short* __restrict__ m4h, short* __restrict__ m4l,
    short* __restrict__ w5h, short* __restrict__ w5l)
{
    const float* src; short* th; short* tl; int Nc;
    switch (blockIdx.y) {
        case 0: src = w1; th = w1h; tl = w1l; Nc = 384; break;
        case 1: src = w2; th = w2h; tl = w2l; Nc = 384; break;
        case 2: src = m1; th = m1h; tl = m1l; Nc = 128; break;
        case 3: src = m2; th = m2h; tl = m2l; Nc = 128; break;
        case 4: src = m3; th = m3h; tl = m3l; Nc = 128; break;
        case 5: src = m4; th = m4h; tl = m4l; Nc = 128; break;
        default: src = w5; th = w5h; tl = w5l; Nc = 6; break;
    }
    int i = blockIdx.x * blockDim.x + threadIdx.x;
    if (i >= 128 * Nc) return;
    int k = i / Nc, c = i - k * Nc;
    float v = src[i];
    short h = f2bf(v);
    th[(size_t)c * 128 + k] = h;
    tl[(size_t)c * 128 + k] = f2bf(v - bf2f(h));
}

// ---------------------------------------------------------------------------
// GEMM: C[M x Nc] = A @ W. A hi/lo planes [M][128], W^T hi/lo planes [Nc][128].
// flags: 1 bias, 2 lrelu(0.01), 4 fused el/er (head = blockIdx.x; Nc=384),
//        8 fp32 C, 16 hi plane, 32 lo plane.
__global__ __launch_bounds__(256) void gemm_mfma(
    const short* __restrict__ Ahi, const short* __restrict__ Alo,
    const short* __restrict__ Bth, const short* __restrict__ Btl,
    const float* __restrict__ bias,
    float* __restrict__ Cf, short* __restrict__ Chi, short* __restrict__ Clo,
    float* __restrict__ el, float* __restrict__ er,
    const float* __restrict__ al, const float* __restrict__ ar,
    int M, int Nc, int flags)
{
    __shared__ short Ah[BM * LSTR], Al_[BM * LSTR];
    __shared__ short Bh[BN * LSTR], Bl_[BN * LSTR];

    int tid = threadIdx.x, lane = tid & 63, wave = tid >> 6;
    int l15 = lane & 15, q = lane >> 4;
    int rowBase = blockIdx.y * BM, colBase = blockIdx.x * BN;

    float4v acc[2][8];
    #pragma unroll
    for (int mt = 0; mt < 2; ++mt)
        #pragma unroll
        for (int nt = 0; nt < 8; ++nt)
            acc[mt][nt] = (float4v){0.f, 0.f, 0.f, 0.f};

    for (int k0 = 0; k0 < 128; k0 += BK) {
        #pragma unroll
        for (int s = 0; s < 2; ++s) {
            int c = tid + s * 256;
            int r = c >> 2, kq = (c & 3) * 8;
            int gr = rowBase + r;
            short8 vh = zero8(), vl = zero8();
            if (gr < M) {
                vh = *(const short8*)(Ahi + (size_t)gr * 128 + k0 + kq);
                vl = *(const short8*)(Alo + (size_t)gr * 128 + k0 + kq);
            }
            *(short8*)&Ah[r * LSTR + kq]  = vh;
            *(short8*)&Al_[r * LSTR + kq] = vl;
            int gc = colBase + r;
            short8 wh = zero8(), wl = zero8();
            if (gc < Nc) {
                wh = *(const short8*)(Bth + (size_t)gc * 128 + k0 + kq);
                wl = *(const short8*)(Btl + (size_t)gc * 128 + k0 + kq);
            }
            *(short8*)&Bh[r * LSTR + kq]  = wh;
            *(short8*)&Bl_[r * LSTR + kq] = wl;
        }
        __syncthreads();

        short8 aH[2], aL2[2];
        #pragma unroll
        for (int mt = 0; mt < 2; ++mt) {
            int off = (wave * 32 + mt * 16 + l15) * LSTR + q * 8;
            aH[mt]  = *(short8*)&Ah[off];
            aL2[mt] = *(short8*)&Al_[off];
        }
        #pragma unroll
        for (int nt = 0; nt < 8; ++nt) {
            int off = (nt * 16 + l15) * LSTR + q * 8;
            short8 bH = *(short8*)&Bh[off];
            short8 bL = *(short8*)&Bl_[off];
            #pragma unroll
            for (int mt = 0; mt < 2; ++mt) {
                acc[mt][nt] = __builtin_amdgcn_mfma_f32_16x16x32_bf16(aH[mt], bH, acc[mt][nt], 0, 0, 0);
                acc[mt][nt] = __builtin_amdgcn_mfma_f32_16x16x32_bf16(aH[mt], bL, acc[mt][nt], 0, 0, 0);
                acc[mt][nt] = __builtin_amdgcn_mfma_f32_16x16x32_bf16(aL2[mt], bH, acc[mt][nt], 0, 0, 0);
            }
        }
        __syncthreads();
    }

    // ---- fused el/er (GAT)
    if (flags & 4) {
        const float* alh = al + colBase;
        const float* arh = ar + colBase;
        float pel[2][4] = {}, per_[2][4] = {};
        #pragma unroll
        for (int nt = 0; nt < 8; ++nt) {
            float av = alh[nt * 16 + l15];
            float rv = arh[nt * 16 + l15];
            #pragma unroll
            for (int mt = 0; mt < 2; ++mt)
                #pragma unroll
                for (int i = 0; i < 4; ++i) {
                    pel[mt][i]  += acc[mt][nt][i] * av;
                    per_[mt][i] += acc[mt][nt][i] * rv;
                }
        }
        #pragma unroll
        for (int mask = 1; mask < 16; mask <<= 1)
            #pragma unroll
            for (int mt = 0; mt < 2; ++mt)
                #pragma unroll
                for (int i = 0; i < 4; ++i) {
                    pel[mt][i]  += __shfl_xor(pel[mt][i], mask);
                    per_[mt][i] += __shfl_xor(per_[mt][i], mask);
                }
        if (l15 == 0) {
            #pragma unroll
            for (int mt = 0; mt < 2; ++mt)
                #pragma unroll
                for (int i = 0; i < 4; ++i) {
                    int r = rowBase + wave * 32 + mt * 16 + q * 4 + i;
                    if (r < M) {
                        el[r * 3 + blockIdx.x] = pel[mt][i];
                        er[r * 3 + blockIdx.x] = per_[mt][i];
                    }
                }
        }
    }

    // ---- C write (node-major)
    #pragma unroll
    for (int mt = 0; mt < 2; ++mt) {
        #pragma unroll
        for (int nt = 0; nt < 8; ++nt) {
            int c = colBase + nt * 16 + l15;
            if (c >= Nc) continue;
            float bv = (flags & 1) ? bias[c] : 0.f;
            #pragma unroll
            for (int i = 0; i < 4; ++i) {
                int r = rowBase + wave * 32 + mt * 16 + q * 4 + i;
                if (r >= M) continue;
                float v = acc[mt][nt][i] + bv;
                if (flags & 2) v = (v < 0.f) ? 0.01f * v : v;
                size_t idx = (size_t)r * Nc + c;
                if (flags & 8)  Cf[idx] = v;
                if (flags & 16) {
                    short hh = f2bf(v);
                    Chi[idx] = hh;
                    if (flags & 32) Clo[idx] = f2bf(v - bf2f(hh));
                }
            }
        }
    }
}

// ---------------------------------------------------------------------------
// CSR build
__global__ void hist_kernel(const int* __restrict__ dst, int* __restrict__ cnt, int E)
{
    int e = blockIdx.x * blockDim.x + threadIdx.x;
    if (e < E) atomicAdd(&cnt[dst[e]], 1);
}

__global__ __launch_bounds__(1024) void scan_block(const int* __restrict__ cnt,
                                                   int* __restrict__ off,
                                                   int* __restrict__ bsum, int n)
{
    __shared__ int tmp[1024];
    int tid = threadIdx.x;
    int i = blockIdx.x * 1024 + tid;
    int v = (i < n) ? cnt[i] : 0;
    tmp[tid] = v;
    __syncthreads();
    for (int s = 1; s < 1024; s <<= 1) {
        int t = (tid >= s) ? tmp[tid - s] : 0;
        __syncthreads();
        tmp[tid] += t;
        __syncthreads();
    }
    if (i < n) off[i] = tmp[tid] - v;
    if (tid == 1023) bsum[blockIdx.x] = tmp[1023];
}

__global__ __launch_bounds__(256) void scan_tops(int* __restrict__ bsum, int nb)
{
    __shared__ int tmp[256];
    int tid = threadIdx.x;
    int v = (tid < nb) ? bsum[tid] : 0;
    tmp[tid] = v;
    __syncthreads();
    for (int s = 1; s < 256; s <<= 1) {
        int t = (tid >= s) ? tmp[tid - s] : 0;
        __syncthreads();
        tmp[tid] += t;
        __syncthreads();
    }
    if (tid < nb) bsum[tid] = tmp[tid] - v;
    if (tid == 0) bsum[nb] = tmp[255];
}

__global__ void scan_add(int* __restrict__ off, const int* __restrict__ bsum,
                         int n, int nb)
{
    int i = blockIdx.x * blockDim.x + threadIdx.x;
    if (i < n) off[i] += bsum[i >> 10];
    if (i == 0) off[n] = bsum[nb];
}

__global__ void scatter_kernel(const int* __restrict__ src, const int* __restrict__ dst,
                               const int* __restrict__ off, int* __restrict__ pcnt,
                               int* __restrict__ csrc, int E)
{
    int e = blockIdx.x * blockDim.x + threadIdx.x;
    if (e < E) {
        int d = dst[e];
        int p = atomicAdd(&pcnt[d], 1);
        csrc[off[d] + p] = src[e];
    }
}

// ---------------------------------------------------------------------------
// One thread per (node, head): edge softmax -> normalized per-edge weight in
// CSR order, walpha[i*3+h].  (R4-proven version.)
__global__ __launch_bounds__(256) void mden_kernel(
    const float* __restrict__ el, const float* __restrict__ er,
    const int* __restrict__ off, const int* __restrict__ csrc,
    float* __restrict__ walpha, int N)
{
    int t = blockIdx.x * blockDim.x + threadIdx.x;
    if (t >= N * 3) return;
    int n = t / 3, hh = t - n * 3;
    int beg = off[n], end = off[n + 1];
    float erh = er[t];
    float m = -1e30f;
    for (int i = beg; i < end; ++i) {
        float e = el[csrc[i] * 3 + hh] + erh;
        e = (e < 0.f) ? 0.2f * e : e;
        m = fmaxf(m, e);
    }
    if (end == beg) return;
    float den = 0.f;
    for (int i = beg; i < end; ++i) {
        float e = el[csrc[i] * 3 + hh] + erh;
        e = (e < 0.f) ? 0.2f * e : e;
        den += __expf(e - m);
    }
    float r = 1.f / (den + 1e-9f);
    for (int i = beg; i < end; ++i) {
        float e = el[csrc[i] * 3 + hh] + erh;
        e = (e < 0.f) ? 0.2f * e : e;
        walpha[i * 3 + hh] = __expf(e - m) * r;
    }
}

// ---------------------------------------------------------------------------
// Weighted gather + bias + lrelu + head-mean. Block per node, 192 threads =
// (head 0..2) x (lane 0..63); each lane owns feature pair (2l, 2l+1) and
// loads one uint (2 bf16) per edge. Weights pre-normalized. R4 structure.
__global__ __launch_bounds__(192) void agg_kernel(
    const short* __restrict__ h, const float* __restrict__ walpha,
    const int* __restrict__ off, const int* __restrict__ csrc,
    const float* __restrict__ bias,
    short* __restrict__ outH, short* __restrict__ outL, int N)
{
    int n = blockIdx.x;
    int tid = threadIdx.x;         // 0..191
    int head = tid >> 6;           // 0..2
    int l = tid & 63;              // feature pair (2l, 2l+1)
    int beg = off[n], end = off[n + 1];
    int deg = end - beg;

    __shared__ int   ssrc[64];
    __shared__ float sw[64 * 3];
    __shared__ float sm[384];

    int fbase = head * 128 + 2 * l;
    float ax = 0.f, ay = 0.f;

    for (int base = 0; base < deg; base += 64) {
        int cnt = min(64, deg - base);
        if (tid < cnt) ssrc[tid] = csrc[beg + base + tid];
        if (tid < cnt * 3) sw[tid] = walpha[(size_t)(beg + base) * 3 + tid];
        __syncthreads();
        #pragma unroll 4
        for (int qq = 0; qq < cnt; ++qq) {
            int s = ssrc[qq];
            float w = sw[qq * 3 + head];
            unsigned v = *(const unsigned*)(h + (size_t)s * 384 + fbase);
            union { unsigned u; float f; } f0, f1;
            f0.u = v << 16; f1.u = v & 0xffff0000u;
            ax += w * f0.f;
            ay += w * f1.f;
        }
        __syncthreads();
    }
    float2 bv = *(const float2*)(bias + fbase);
    float vx = ax + bv.x; vx = (vx < 0.f) ? 0.01f * vx : vx;
    float vy = ay + bv.y; vy = (vy < 0.f) ? 0.01f * vy : vy;
    sm[fbase]     = vx;
    sm[fbase + 1] = vy;
    __syncthreads();
    if (tid < 64) {
        int f0i = tid * 2, f1i = f0i + 1;
        float mx = (sm[f0i] + sm[128 + f0i] + sm[256 + f0i]) * (1.0f / 3.0f);
        float my = (sm[f1i] + sm[128 + f1i] + sm[256 + f1i]) * (1.0f / 3.0f);
        short hx = f2bf(mx), lx = f2bf(mx - bf2f(hx));
        short hy = f2bf(my), ly = f2bf(my - bf2f(hy));
        unsigned ph = (unsigned)(unsigned short)hx | ((unsigned)(unsigned short)hy << 16);
        unsigned pl = (unsigned)(unsigned short)lx | ((unsigned)(unsigned short)ly << 16);
        *(unsigned*)(outH + (size_t)n * 128 + f0i) = ph;
        *(unsigned*)(outL + (size_t)n * 128 + f0i) = pl;
    }
}

// ---------------------------------------------------------------------------
extern "C" void kernel_launch(void* const* d_in, const int* in_sizes, int n_in,
                              void* d_out, int out_size, void* d_ws, size_t ws_size,
                              hipStream_t stream)
{
    const float* in_feat = (const float*)d_in[0];
    const int*   src     = (const int*)d_in[1];
    const int*   dst     = (const int*)d_in[2];
    const float* W1  = (const float*)d_in[3];
    const float* al1 = (const float*)d_in[4];
    const float* ar1 = (const float*)d_in[5];
    const float* b1  = (const float*)d_in[6];
    const float* W2  = (const float*)d_in[7];
    const float* al2 = (const float*)d_in[8];
    const float* ar2 = (const float*)d_in[9];
    const float* b2  = (const float*)d_in[10];
    const float* lw1 = (const float*)d_in[11];
    const float* lb1 = (const float*)d_in[12];
    const float* lw2 = (const float*)d_in[13];
    const float* lb2 = (const float*)d_in[14];
    const float* lw3 = (const float*)d_in[15];
    const float* lb3 = (const float*)d_in[16];
    const float* lw4 = (const float*)d_in[17];
    const float* lb4 = (const float*)d_in[18];
    const float* lw5 = (const float*)d_in[19];
    const float* lb5 = (const float*)d_in[20];

    const int N = in_sizes[0] / 128;   // 50000
    const int E = in_sizes[1];         // 800000

    size_t o = 0;
    auto alloc = [&](size_t bytes) { size_t p = o; o = (o + bytes + 255) & ~(size_t)255; return p; };
    char* ws = (char*)d_ws;
    short* P1h = (short*)(ws + alloc((size_t)N * 128 * 2));
    short* P1l = (short*)(ws + alloc((size_t)N * 128 * 2));
    short* P2h = (short*)(ws + alloc((size_t)N * 128 * 2));
    short* P2l = (short*)(ws + alloc((size_t)N * 128 * 2));
    short* AbH = (short*)(ws + alloc((size_t)N * 384 * 2));   // GAT gemm out, hi, node-major
    float* el  = (float*)(ws + alloc((size_t)N * 3 * 4));
    float* er  = (float*)(ws + alloc((size_t)N * 3 * 4));
    int*   cnt  = (int*)(ws + alloc((size_t)N * 4));
    int*   pcnt = (int*)(ws + alloc((size_t)N * 4));
    int*   off  = (int*)(ws + alloc((size_t)(N + 1) * 4));
    int*   bsum = (int*)(ws + alloc((size_t)4096));
    int*   csrc = (int*)(ws + alloc((size_t)E * 4));
    float* walpha = (float*)(ws + alloc((size_t)E * 3 * 4));  // [E][3]
    short* w1th = (short*)(ws + alloc((size_t)384 * 128 * 2));
    short* w1tl = (short*)(ws + alloc((size_t)384 * 128 * 2));
    short* w2th = (short*)(ws + alloc((size_t)384 * 128 * 2));
    short* w2tl = (short*)(ws + alloc((size_t)384 * 128 * 2));
    short* l1th = (short*)(ws + alloc((size_t)128 * 128 * 2));
    short* l1tl = (short*)(ws + alloc((size_t)128 * 128 * 2));
    short* l2th = (short*)(ws + alloc((size_t)128 * 128 * 2));
    short* l2tl = (short*)(ws + alloc((size_t)128 * 128 * 2));
    short* l3th = (short*)(ws + alloc((size_t)128 * 128 * 2));
    short* l3tl = (short*)(ws + alloc((size_t)128 * 128 * 2));
    short* l4th = (short*)(ws + alloc((size_t)128 * 128 * 2));
    short* l4tl = (short*)(ws + alloc((size_t)128 * 128 * 2));
    short* l5th = (short*)(ws + alloc((size_t)6 * 128 * 2));
    short* l5tl = (short*)(ws + alloc((size_t)6 * 128 * 2));
    (void)ws_size;

    float* out = (float*)d_out;

    // ---- input/weight conversions (2 launches)
    conv_split<<<(N * 128 / 4 + 255) / 256, 256, 0, stream>>>(in_feat, P1h, P1l, N * 128 / 4);
    {
        dim3 grid((128 * 384 + 255) / 256, 7);
        convw_all<<<grid, 256, 0, stream>>>(W1, W2, lw1, lw2, lw3, lw4, lw5,
                                            w1th, w1tl, w2th, w2tl,
                                            l1th, l1tl, l2th, l2tl,
                                            l3th, l3tl, l4th, l4tl,
                                            l5th, l5tl);
    }

    // ---- CSR build
    hipMemsetAsync(cnt, 0, (size_t)N * 4, stream);
    hipMemsetAsync(pcnt, 0, (size_t)N * 4, stream);
    hist_kernel<<<(E + 255) / 256, 256, 0, stream>>>(dst, cnt, E);
    int nb = (N + 1023) / 1024;
    scan_block<<<nb, 1024, 0, stream>>>(cnt, off, bsum, N);
    scan_tops<<<1, 256, 0, stream>>>(bsum, nb);
    scan_add<<<(N + 255) / 256, 256, 0, stream>>>(off, bsum, N, nb);
    scatter_kernel<<<(E + 255) / 256, 256, 0, stream>>>(src, dst, off, pcnt, csrc, E);

    int RB = (N + BM - 1) / BM;
    auto gemm = [&](const short* ah, const short* alo, const short* bth, const short* btl,
                    const float* bias, float* cf, short* chi, short* clo,
                    float* elp, float* erp, const float* alp, const float* arp,
                    int Nc, int flags) {
        dim3 grid((Nc + BN - 1) / BN, RB);
        gemm_mfma<<<grid, 256, 0, stream>>>(ah, alo, bth, btl, bias, cf, chi, clo,
                                            elp, erp, alp, arp, N, Nc, flags);
    };
    int nh_blocks = (N * 3 + 255) / 256;

    // ---- GAT layer 1
    gemm(P1h, P1l, w1th, w1tl, nullptr, nullptr, AbH, nullptr, el, er, al1, ar1, 384, 4 | 16);
    mden_kernel<<<nh_blocks, 256, 0, stream>>>(el, er, off, csrc, walpha, N);
    agg_kernel<<<N, 192, 0, stream>>>(AbH, walpha, off, csrc, b1, P2h, P2l, N);

    // ---- GAT layer 2
    gemm(P2h, P2l, w2th, w2tl, nullptr, nullptr, AbH, nullptr, el, er, al2, ar2, 384, 4 | 16);
    mden_kernel<<<nh_blocks, 256, 0, stream>>>(el, er, off, csrc, walpha, N);
    agg_kernel<<<N, 192, 0, stream>>>(AbH, walpha, off, csrc, b2, P1h, P1l, N);

    // ---- MLP head
    gemm(P1h, P1l, l1th, l1tl, lb1, nullptr, P2h, P2l, nullptr, nullptr, nullptr, nullptr, 128, 1 | 2 | 16 | 32);
    gemm(P2h, P2l, l2th, l2tl, lb2, nullptr, P1h, P1l, nullptr, nullptr, nullptr, nullptr, 128, 1 | 2 | 16 | 32);
    gemm(P1h, P1l, l3th, l3tl, lb3, nullptr, P2h, P2l, nullptr, nullptr, nullptr, nullptr, 128, 1 | 2 | 16 | 32);
    gemm(P2h, P2l, l4th, l4tl, lb4, nullptr, P1h, P1l, nullptr, nullptr, nullptr, nullptr, 128, 1 | 2 | 16 | 32);
    gemm(P1h, P1l, l5th, l5tl, lb5, out, nullptr, nullptr, nullptr, nullptr, nullptr, nullptr, 6, 1 | 8);
}

// Round 8
// 644.528 us; speedup vs baseline: 1.3395x; 1.0728x over previous
//
#include <hip/hip_runtime.h>
#include <hip/hip_bf16.h>

// ---------------------------------------------------------------------------
// GAT (2 GATConv + 5-layer MLP), MI355X.
// R4 (proven): bf16 hi/lo planes end-to-end, split-bf16 MFMA (3 terms),
//     fused el/er in GEMM epilogue, mden thread-per-(node,head),
//     agg block-per-node edge-parallel gather (R7: 2 feats/lane uint loads).
// R8: lin1..lin5 fused into one kernel (mlp_fused): activations ping-pong in
//     LDS hi/lo planes, weights staged per-BK chunk; deletes 5 GEMM launches
//     + 4 intermediate plane round-trips. mden 3rd pass streams walpha.
// ---------------------------------------------------------------------------

typedef __attribute__((ext_vector_type(8))) short short8;   // 8 bf16 = 4 VGPR
typedef __attribute__((ext_vector_type(4))) float float4v;  // MFMA C/D

__device__ inline short f2bf(float x) {
    union { float f; unsigned u; } v; v.f = x;
    unsigned r = v.u + 0x7FFFu + ((v.u >> 16) & 1u);   // RNE
    return (short)(r >> 16);
}
__device__ inline float bf2f(short b) {
    union { float f; unsigned u; } v;
    v.u = ((unsigned)(unsigned short)b) << 16;
    return v.f;
}
__device__ inline short8 zero8() { short8 z = {0,0,0,0,0,0,0,0}; return z; }

#define BM 128
#define BN 128
#define BK 32
#define LSTR 40    // LDS row stride in shorts (80 B, 16B-aligned, breaks pow2)
#define MSTR 136   // act row stride in shorts (272 B = 17x16B, breaks pow2)

// ---------------------------------------------------------------------------
__global__ void conv_split(const float* __restrict__ x, short* __restrict__ hi,
                           short* __restrict__ lo, int n4)
{
    int i = blockIdx.x * blockDim.x + threadIdx.x;
    if (i >= n4) return;
    float4 v = *(const float4*)(x + (size_t)i * 4);
    float xs[4] = {v.x, v.y, v.z, v.w};
    short hs[4], ls[4];
    #pragma unroll
    for (int j = 0; j < 4; ++j) {
        hs[j] = f2bf(xs[j]);
        ls[j] = f2bf(xs[j] - bf2f(hs[j]));
    }
    *(uint2*)(hi + (size_t)i * 4) = *(uint2*)hs;
    *(uint2*)(lo + (size_t)i * 4) = *(uint2*)ls;
}

// All 7 weight matrices: fp32 [128][Nc] -> transposed bf16 hi/lo [Nc][128].
__global__ void convw_all(
    const float* __restrict__ w1, const float* __restrict__ w2,
    const float* __restrict__ m1, const float* __restrict__ m2,
    const float* __restrict__ m3, const float* __restrict__ m4,
    const float* __restrict__ w5,
    short* __restrict__ w1h, short* __restrict__ w1l,
    short* __restrict__ w2h, short* __restrict__ w2l,
    short* __restrict__ m1h, short* __restrict__ m1l,
    short* __restrict__ m2h, short* __restrict__ m2l,
    short* __restrict__ m3h, short* __restrict__ m3l,
    short* __restrict__ m4h, short* __restrict__ m4l,
    short* __restrict__ w5h, short* __restrict__ w5l)
{
    const float* src; short* th; short* tl; int Nc;
    switch (blockIdx.y) {
        case 0: src = w1; th = w1h; tl = w1l; Nc = 384; break;
        case 1: src = w2; th = w2h; tl = w2l; Nc = 384; break;
        case 2: src = m1; th = m1h; tl = m1l; Nc = 128; break;
        case 3: src = m2; th = m2h; tl = m2l; Nc = 128; break;
        case 4: src = m3; th = m3h; tl = m3l; Nc = 128; break;
        case 5: src = m4; th = m4h; tl = m4l; Nc = 128; break;
        default: src = w5; th = w5h; tl = w5l; Nc = 6; break;
    }
    int i = blockIdx.x * blockDim.x + threadIdx.x;
    if (i >= 128 * Nc) return;
    int k = i / Nc, c = i - k * Nc;
    float v = src[i];
    short h = f2bf(v);
    th[(size_t)c * 128 + k] = h;
    tl[(size_t)c * 128 + k] = f2bf(v - bf2f(h));
}

// ---------------------------------------------------------------------------
// GEMM (GAT layers): C[M x Nc] = A @ W, fused el/er. flags as before.
__global__ __launch_bounds__(256) void gemm_mfma(
    const short* __restrict__ Ahi, const short* __restrict__ Alo,
    const short* __restrict__ Bth, const short* __restrict__ Btl,
    const float* __restrict__ bias,
    float* __restrict__ Cf, short* __restrict__ Chi, short* __restrict__ Clo,
    float* __restrict__ el, float* __restrict__ er,
    const float* __restrict__ al, const float* __restrict__ ar,
    int M, int Nc, int flags)
{
    __shared__ short Ah[BM * LSTR], Al_[BM * LSTR];
    __shared__ short Bh[BN * LSTR], Bl_[BN * LSTR];

    int tid = threadIdx.x, lane = tid & 63, wave = tid >> 6;
    int l15 = lane & 15, q = lane >> 4;
    int rowBase = blockIdx.y * BM, colBase = blockIdx.x * BN;

    float4v acc[2][8];
    #pragma unroll
    for (int mt = 0; mt < 2; ++mt)
        #pragma unroll
        for (int nt = 0; nt < 8; ++nt)
            acc[mt][nt] = (float4v){0.f, 0.f, 0.f, 0.f};

    for (int k0 = 0; k0 < 128; k0 += BK) {
        #pragma unroll
        for (int s = 0; s < 2; ++s) {
            int c = tid + s * 256;
            int r = c >> 2, kq = (c & 3) * 8;
            int gr = rowBase + r;
            short8 vh = zero8(), vl = zero8();
            if (gr < M) {
                vh = *(const short8*)(Ahi + (size_t)gr * 128 + k0 + kq);
                vl = *(const short8*)(Alo + (size_t)gr * 128 + k0 + kq);
            }
            *(short8*)&Ah[r * LSTR + kq]  = vh;
            *(short8*)&Al_[r * LSTR + kq] = vl;
            int gc = colBase + r;
            short8 wh = zero8(), wl = zero8();
            if (gc < Nc) {
                wh = *(const short8*)(Bth + (size_t)gc * 128 + k0 + kq);
                wl = *(const short8*)(Btl + (size_t)gc * 128 + k0 + kq);
            }
            *(short8*)&Bh[r * LSTR + kq]  = wh;
            *(short8*)&Bl_[r * LSTR + kq] = wl;
        }
        __syncthreads();

        short8 aH[2], aL2[2];
        #pragma unroll
        for (int mt = 0; mt < 2; ++mt) {
            int off = (wave * 32 + mt * 16 + l15) * LSTR + q * 8;
            aH[mt]  = *(short8*)&Ah[off];
            aL2[mt] = *(short8*)&Al_[off];
        }
        #pragma unroll
        for (int nt = 0; nt < 8; ++nt) {
            int off = (nt * 16 + l15) * LSTR + q * 8;
            short8 bH = *(short8*)&Bh[off];
            short8 bL = *(short8*)&Bl_[off];
            #pragma unroll
            for (int mt = 0; mt < 2; ++mt) {
                acc[mt][nt] = __builtin_amdgcn_mfma_f32_16x16x32_bf16(aH[mt], bH, acc[mt][nt], 0, 0, 0);
                acc[mt][nt] = __builtin_amdgcn_mfma_f32_16x16x32_bf16(aH[mt], bL, acc[mt][nt], 0, 0, 0);
                acc[mt][nt] = __builtin_amdgcn_mfma_f32_16x16x32_bf16(aL2[mt], bH, acc[mt][nt], 0, 0, 0);
            }
        }
        __syncthreads();
    }

    if (flags & 4) {
        const float* alh = al + colBase;
        const float* arh = ar + colBase;
        float pel[2][4] = {}, per_[2][4] = {};
        #pragma unroll
        for (int nt = 0; nt < 8; ++nt) {
            float av = alh[nt * 16 + l15];
            float rv = arh[nt * 16 + l15];
            #pragma unroll
            for (int mt = 0; mt < 2; ++mt)
                #pragma unroll
                for (int i = 0; i < 4; ++i) {
                    pel[mt][i]  += acc[mt][nt][i] * av;
                    per_[mt][i] += acc[mt][nt][i] * rv;
                }
        }
        #pragma unroll
        for (int mask = 1; mask < 16; mask <<= 1)
            #pragma unroll
            for (int mt = 0; mt < 2; ++mt)
                #pragma unroll
                for (int i = 0; i < 4; ++i) {
                    pel[mt][i]  += __shfl_xor(pel[mt][i], mask);
                    per_[mt][i] += __shfl_xor(per_[mt][i], mask);
                }
        if (l15 == 0) {
            #pragma unroll
            for (int mt = 0; mt < 2; ++mt)
                #pragma unroll
                for (int i = 0; i < 4; ++i) {
                    int r = rowBase + wave * 32 + mt * 16 + q * 4 + i;
                    if (r < M) {
                        el[r * 3 + blockIdx.x] = pel[mt][i];
                        er[r * 3 + blockIdx.x] = per_[mt][i];
                    }
                }
        }
    }

    #pragma unroll
    for (int mt = 0; mt < 2; ++mt) {
        #pragma unroll
        for (int nt = 0; nt < 8; ++nt) {
            int c = colBase + nt * 16 + l15;
            if (c >= Nc) continue;
            float bv = (flags & 1) ? bias[c] : 0.f;
            #pragma unroll
            for (int i = 0; i < 4; ++i) {
                int r = rowBase + wave * 32 + mt * 16 + q * 4 + i;
                if (r >= M) continue;
                float v = acc[mt][nt][i] + bv;
                if (flags & 2) v = (v < 0.f) ? 0.01f * v : v;
                size_t idx = (size_t)r * Nc + c;
                if (flags & 8)  Cf[idx] = v;
                if (flags & 16) {
                    short hh = f2bf(v);
                    Chi[idx] = hh;
                    if (flags & 32) Clo[idx] = f2bf(v - bf2f(hh));
                }
            }
        }
    }
}

// ---------------------------------------------------------------------------
// Fused MLP head: 4x (128->128, bias, lrelu) + (128->6, bias) in one kernel.
// Block = 128 nodes, 256 threads. Activations live in LDS as hi/lo planes;
// same split-bf16 3-term MFMA and rounding points as gemm_mfma (bit-compat).
__global__ __launch_bounds__(256) void mlp_fused(
    const short* __restrict__ Ph, const short* __restrict__ Pl,
    const short* __restrict__ w1h, const short* __restrict__ w1l,
    const short* __restrict__ w2h, const short* __restrict__ w2l,
    const short* __restrict__ w3h, const short* __restrict__ w3l,
    const short* __restrict__ w4h, const short* __restrict__ w4l,
    const short* __restrict__ w5h, const short* __restrict__ w5l,
    const float* __restrict__ b1, const float* __restrict__ b2,
    const float* __restrict__ b3, const float* __restrict__ b4,
    const float* __restrict__ b5,
    float* __restrict__ out, int M)
{
    __shared__ short AH[128 * MSTR], AL[128 * MSTR];   // activations hi/lo
    __shared__ short WH[128 * LSTR], WL[128 * LSTR];   // weight BK-chunk

    int tid = threadIdx.x, lane = tid & 63, wave = tid >> 6;
    int l15 = lane & 15, q = lane >> 4;
    int rowBase = blockIdx.x * 128;

    // ---- initial act staging (full 128 rows x 128 k, hi+lo)
    #pragma unroll
    for (int s = 0; s < 8; ++s) {
        int idx = tid + s * 256;          // 2048 slots = 128 rows x 16 chunks
        int r = idx >> 4, kq = (idx & 15) * 8;
        int gr = rowBase + r;
        short8 vh = zero8(), vl = zero8();
        if (gr < M) {
            vh = *(const short8*)(Ph + (size_t)gr * 128 + kq);
            vl = *(const short8*)(Pl + (size_t)gr * 128 + kq);
        }
        *(short8*)&AH[r * MSTR + kq] = vh;
        *(short8*)&AL[r * MSTR + kq] = vl;
    }

    const short* Whs[4] = {w1h, w2h, w3h, w4h};
    const short* Wls[4] = {w1l, w2l, w3l, w4l};
    const float* Bss[4] = {b1, b2, b3, b4};

    #pragma unroll
    for (int L = 0; L < 4; ++L) {
        float4v acc[2][8];
        #pragma unroll
        for (int mt = 0; mt < 2; ++mt)
            #pragma unroll
            for (int nt = 0; nt < 8; ++nt)
                acc[mt][nt] = (float4v){0.f, 0.f, 0.f, 0.f};

        for (int k0 = 0; k0 < 128; k0 += BK) {
            // stage W chunk (128 cols x 32 k, hi+lo): 1024 short8 slots
            #pragma unroll
            for (int s = 0; s < 4; ++s) {
                int idx = tid + s * 256;
                int plane = idx >> 9, rem = idx & 511;
                int c = rem >> 2, kq = (rem & 3) * 8;
                short8 v = *(const short8*)((plane ? Wls[L] : Whs[L]) +
                                            (size_t)c * 128 + k0 + kq);
                *(short8*)&((plane ? WL : WH)[c * LSTR + kq]) = v;
            }
            __syncthreads();
            short8 aH[2], aL2[2];
            #pragma unroll
            for (int mt = 0; mt < 2; ++mt) {
                int off = (wave * 32 + mt * 16 + l15) * MSTR + k0 + q * 8;
                aH[mt]  = *(short8*)&AH[off];
                aL2[mt] = *(short8*)&AL[off];
            }
            #pragma unroll
            for (int nt = 0; nt < 8; ++nt) {
                int off = (nt * 16 + l15) * LSTR + q * 8;
                short8 bH = *(short8*)&WH[off];
                short8 bL = *(short8*)&WL[off];
                #pragma unroll
                for (int mt = 0; mt < 2; ++mt) {
                    acc[mt][nt] = __builtin_amdgcn_mfma_f32_16x16x32_bf16(aH[mt], bH, acc[mt][nt], 0, 0, 0);
                    acc[mt][nt] = __builtin_amdgcn_mfma_f32_16x16x32_bf16(aH[mt], bL, acc[mt][nt], 0, 0, 0);
                    acc[mt][nt] = __builtin_amdgcn_mfma_f32_16x16x32_bf16(aL2[mt], bH, acc[mt][nt], 0, 0, 0);
                }
            }
            __syncthreads();   // all act/W reads done before epilogue writes
        }
        // epilogue: bias + lrelu, write act hi/lo in place
        #pragma unroll
        for (int mt = 0; mt < 2; ++mt) {
            #pragma unroll
            for (int nt = 0; nt < 8; ++nt) {
                int c = nt * 16 + l15;
                float bv = Bss[L][c];
                #pragma unroll
                for (int i = 0; i < 4; ++i) {
                    int r = wave * 32 + mt * 16 + q * 4 + i;
                    float v = acc[mt][nt][i] + bv;
                    v = (v < 0.f) ? 0.01f * v : v;
                    short hh = f2bf(v);
                    AH[r * MSTR + c] = hh;
                    AL[r * MSTR + c] = f2bf(v - bf2f(hh));
                }
            }
        }
        __syncthreads();       // act writes visible before next layer reads
    }

    // ---- lin5: 128 -> 6, bias, fp32 out
    float4v acc5[2];
    acc5[0] = (float4v){0.f, 0.f, 0.f, 0.f};
    acc5[1] = (float4v){0.f, 0.f, 0.f, 0.f};
    for (int k0 = 0; k0 < 128; k0 += BK) {
        // stage 16 cols x 32 k, zero-filled beyond col 6; 128 slots
        if (tid < 128) {
            int plane = tid >> 6, rem = tid & 63;
            int c = rem >> 2, kq = (rem & 3) * 8;
            short8 v = zero8();
            if (c < 6)
                v = *(const short8*)((plane ? w5l : w5h) + (size_t)c * 128 + k0 + kq);
            *(short8*)&((plane ? WL : WH)[c * LSTR + kq]) = v;
        }
        __syncthreads();
        short8 aH[2], aL2[2];
        #pragma unroll
        for (int mt = 0; mt < 2; ++mt) {
            int off = (wave * 32 + mt * 16 + l15) * MSTR + k0 + q * 8;
            aH[mt]  = *(short8*)&AH[off];
            aL2[mt] = *(short8*)&AL[off];
        }
        int offb = l15 * LSTR + q * 8;
        short8 bH = *(short8*)&WH[offb];
        short8 bL = *(short8*)&WL[offb];
        #pragma unroll
        for (int mt = 0; mt < 2; ++mt) {
            acc5[mt] = __builtin_amdgcn_mfma_f32_16x16x32_bf16(aH[mt], bH, acc5[mt], 0, 0, 0);
            acc5[mt] = __builtin_amdgcn_mfma_f32_16x16x32_bf16(aH[mt], bL, acc5[mt], 0, 0, 0);
            acc5[mt] = __builtin_amdgcn_mfma_f32_16x16x32_bf16(aL2[mt], bH, acc5[mt], 0, 0, 0);
        }
        __syncthreads();
    }
    if (l15 < 6) {
        float bv = b5[l15];
        #pragma unroll
        for (int mt = 0; mt < 2; ++mt)
            #pragma unroll
            for (int i = 0; i < 4; ++i) {
                int r = rowBase + wave * 32 + mt * 16 + q * 4 + i;
                if (r < M) out[(size_t)r * 6 + l15] = acc5[mt][i] + bv;
            }
    }
}

// ---------------------------------------------------------------------------
// CSR build
__global__ void hist_kernel(const int* __restrict__ dst, int* __restrict__ cnt, int E)
{
    int e = blockIdx.x * blockDim.x + threadIdx.x;
    if (e < E) atomicAdd(&cnt[dst[e]], 1);
}

__global__ __launch_bounds__(1024) void scan_block(const int* __restrict__ cnt,
                                                   int* __restrict__ off,
                                                   int* __restrict__ bsum, int n)
{
    __shared__ int tmp[1024];
    int tid = threadIdx.x;
    int i = blockIdx.x * 1024 + tid;
    int v = (i < n) ? cnt[i] : 0;
    tmp[tid] = v;
    __syncthreads();
    for (int s = 1; s < 1024; s <<= 1) {
        int t = (tid >= s) ? tmp[tid - s] : 0;
        __syncthreads();
        tmp[tid] += t;
        __syncthreads();
    }
    if (i < n) off[i] = tmp[tid] - v;
    if (tid == 1023) bsum[blockIdx.x] = tmp[1023];
}

__global__ __launch_bounds__(256) void scan_tops(int* __restrict__ bsum, int nb)
{
    __shared__ int tmp[256];
    int tid = threadIdx.x;
    int v = (tid < nb) ? bsum[tid] : 0;
    tmp[tid] = v;
    __syncthreads();
    for (int s = 1; s < 256; s <<= 1) {
        int t = (tid >= s) ? tmp[tid - s] : 0;
        __syncthreads();
        tmp[tid] += t;
        __syncthreads();
    }
    if (tid < nb) bsum[tid] = tmp[tid] - v;
    if (tid == 0) bsum[nb] = tmp[255];
}

__global__ void scan_add(int* __restrict__ off, const int* __restrict__ bsum,
                         int n, int nb)
{
    int i = blockIdx.x * blockDim.x + threadIdx.x;
    if (i < n) off[i] += bsum[i >> 10];
    if (i == 0) off[n] = bsum[nb];
}

__global__ void scatter_kernel(const int* __restrict__ src, const int* __restrict__ dst,
                               const int* __restrict__ off, int* __restrict__ pcnt,
                               int* __restrict__ csrc, int E)
{
    int e = blockIdx.x * blockDim.x + threadIdx.x;
    if (e < E) {
        int d = dst[e];
        int p = atomicAdd(&pcnt[d], 1);
        csrc[off[d] + p] = src[e];
    }
}

// ---------------------------------------------------------------------------
// One thread per (node, head): edge softmax -> normalized per-edge weight in
// CSR order, walpha[i*3+h]. R8: pass 3 streams walpha (no 3rd el gather).
__global__ __launch_bounds__(256) void mden_kernel(
    const float* __restrict__ el, const float* __restrict__ er,
    const int* __restrict__ off, const int* __restrict__ csrc,
    float* __restrict__ walpha, int N)
{
    int t = blockIdx.x * blockDim.x + threadIdx.x;
    if (t >= N * 3) return;
    int n = t / 3, hh = t - n * 3;
    int beg = off[n], end = off[n + 1];
    float erh = er[t];
    float m = -1e30f;
    for (int i = beg; i < end; ++i) {
        float e = el[csrc[i] * 3 + hh] + erh;
        e = (e < 0.f) ? 0.2f * e : e;
        m = fmaxf(m, e);
    }
    if (end == beg) return;
    float den = 0.f;
    for (int i = beg; i < end; ++i) {
        float e = el[csrc[i] * 3 + hh] + erh;
        e = (e < 0.f) ? 0.2f * e : e;
        float w = __expf(e - m);
        den += w;
        walpha[i * 3 + hh] = w;
    }
    float r = 1.f / (den + 1e-9f);
    for (int i = beg; i < end; ++i)
        walpha[i * 3 + hh] *= r;
}

// ---------------------------------------------------------------------------
// Weighted gather + bias + lrelu + head-mean. Block per node, 192 threads =
// (head 0..2) x (lane 0..63); lane owns feature pair (2l, 2l+1). R7-proven.
__global__ __launch_bounds__(192) void agg_kernel(
    const short* __restrict__ h, const float* __restrict__ walpha,
    const int* __restrict__ off, const int* __restrict__ csrc,
    const float* __restrict__ bias,
    short* __restrict__ outH, short* __restrict__ outL, int N)
{
    int n = blockIdx.x;
    int tid = threadIdx.x;         // 0..191
    int head = tid >> 6;           // 0..2
    int l = tid & 63;              // feature pair (2l, 2l+1)
    int beg = off[n], end = off[n + 1];
    int deg = end - beg;

    __shared__ int   ssrc[64];
    __shared__ float sw[64 * 3];
    __shared__ float sm[384];

    int fbase = head * 128 + 2 * l;
    float ax = 0.f, ay = 0.f;

    for (int base = 0; base < deg; base += 64) {
        int cnt = min(64, deg - base);
        if (tid < cnt) ssrc[tid] = csrc[beg + base + tid];
        if (tid < cnt * 3) sw[tid] = walpha[(size_t)(beg + base) * 3 + tid];
        __syncthreads();
        #pragma unroll 4
        for (int qq = 0; qq < cnt; ++qq) {
            int s = ssrc[qq];
            float w = sw[qq * 3 + head];
            unsigned v = *(const unsigned*)(h + (size_t)s * 384 + fbase);
            union { unsigned u; float f; } f0, f1;
            f0.u = v << 16; f1.u = v & 0xffff0000u;
            ax += w * f0.f;
            ay += w * f1.f;
        }
        __syncthreads();
    }
    float2 bv = *(const float2*)(bias + fbase);
    float vx = ax + bv.x; vx = (vx < 0.f) ? 0.01f * vx : vx;
    float vy = ay + bv.y; vy = (vy < 0.f) ? 0.01f * vy : vy;
    sm[fbase]     = vx;
    sm[fbase + 1] = vy;
    __syncthreads();
    if (tid < 64) {
        int f0i = tid * 2, f1i = f0i + 1;
        float mx = (sm[f0i] + sm[128 + f0i] + sm[256 + f0i]) * (1.0f / 3.0f);
        float my = (sm[f1i] + sm[128 + f1i] + sm[256 + f1i]) * (1.0f / 3.0f);
        short hx = f2bf(mx), lx = f2bf(mx - bf2f(hx));
        short hy = f2bf(my), ly = f2bf(my - bf2f(hy));
        unsigned ph = (unsigned)(unsigned short)hx | ((unsigned)(unsigned short)hy << 16);
        unsigned pl = (unsigned)(unsigned short)lx | ((unsigned)(unsigned short)ly << 16);
        *(unsigned*)(outH + (size_t)n * 128 + f0i) = ph;
        *(unsigned*)(outL + (size_t)n * 128 + f0i) = pl;
    }
}

// ---------------------------------------------------------------------------
extern "C" void kernel_launch(void* const* d_in, const int* in_sizes, int n_in,
                              void* d_out, int out_size, void* d_ws, size_t ws_size,
                              hipStream_t stream)
{
    const float* in_feat = (const float*)d_in[0];
    const int*   src     = (const int*)d_in[1];
    const int*   dst     = (const int*)d_in[2];
    const float* W1  = (const float*)d_in[3];
    const float* al1 = (const float*)d_in[4];
    const float* ar1 = (const float*)d_in[5];
    const float* b1  = (const float*)d_in[6];
    const float* W2  = (const float*)d_in[7];
    const float* al2 = (const float*)d_in[8];
    const float* ar2 = (const float*)d_in[9];
    const float* b2  = (const float*)d_in[10];
    const float* lw1 = (const float*)d_in[11];
    const float* lb1 = (const float*)d_in[12];
    const float* lw2 = (const float*)d_in[13];
    const float* lb2 = (const float*)d_in[14];
    const float* lw3 = (const float*)d_in[15];
    const float* lb3 = (const float*)d_in[16];
    const float* lw4 = (const float*)d_in[17];
    const float* lb4 = (const float*)d_in[18];
    const float* lw5 = (const float*)d_in[19];
    const float* lb5 = (const float*)d_in[20];

    const int N = in_sizes[0] / 128;   // 50000
    const int E = in_sizes[1];         // 800000

    size_t o = 0;
    auto alloc = [&](size_t bytes) { size_t p = o; o = (o + bytes + 255) & ~(size_t)255; return p; };
    char* ws = (char*)d_ws;
    short* P1h = (short*)(ws + alloc((size_t)N * 128 * 2));
    short* P1l = (short*)(ws + alloc((size_t)N * 128 * 2));
    short* P2h = (short*)(ws + alloc((size_t)N * 128 * 2));
    short* P2l = (short*)(ws + alloc((size_t)N * 128 * 2));
    short* AbH = (short*)(ws + alloc((size_t)N * 384 * 2));   // GAT gemm out, hi, node-major
    float* el  = (float*)(ws + alloc((size_t)N * 3 * 4));
    float* er  = (float*)(ws + alloc((size_t)N * 3 * 4));
    int*   cnt  = (int*)(ws + alloc((size_t)N * 4));
    int*   pcnt = (int*)(ws + alloc((size_t)N * 4));
    int*   off  = (int*)(ws + alloc((size_t)(N + 1) * 4));
    int*   bsum = (int*)(ws + alloc((size_t)4096));
    int*   csrc = (int*)(ws + alloc((size_t)E * 4));
    float* walpha = (float*)(ws + alloc((size_t)E * 3 * 4));  // [E][3]
    short* w1th = (short*)(ws + alloc((size_t)384 * 128 * 2));
    short* w1tl = (short*)(ws + alloc((size_t)384 * 128 * 2));
    short* w2th = (short*)(ws + alloc((size_t)384 * 128 * 2));
    short* w2tl = (short*)(ws + alloc((size_t)384 * 128 * 2));
    short* l1th = (short*)(ws + alloc((size_t)128 * 128 * 2));
    short* l1tl = (short*)(ws + alloc((size_t)128 * 128 * 2));
    short* l2th = (short*)(ws + alloc((size_t)128 * 128 * 2));
    short* l2tl = (short*)(ws + alloc((size_t)128 * 128 * 2));
    short* l3th = (short*)(ws + alloc((size_t)128 * 128 * 2));
    short* l3tl = (short*)(ws + alloc((size_t)128 * 128 * 2));
    short* l4th = (short*)(ws + alloc((size_t)128 * 128 * 2));
    short* l4tl = (short*)(ws + alloc((size_t)128 * 128 * 2));
    short* l5th = (short*)(ws + alloc((size_t)6 * 128 * 2));
    short* l5tl = (short*)(ws + alloc((size_t)6 * 128 * 2));
    (void)ws_size;

    float* out = (float*)d_out;

    // ---- input/weight conversions
    conv_split<<<(N * 128 / 4 + 255) / 256, 256, 0, stream>>>(in_feat, P1h, P1l, N * 128 / 4);
    {
        dim3 grid((128 * 384 + 255) / 256, 7);
        convw_all<<<grid, 256, 0, stream>>>(W1, W2, lw1, lw2, lw3, lw4, lw5,
                                            w1th, w1tl, w2th, w2tl,
                                            l1th, l1tl, l2th, l2tl,
                                            l3th, l3tl, l4th, l4tl,
                                            l5th, l5tl);
    }

    // ---- CSR build
    hipMemsetAsync(cnt, 0, (size_t)N * 4, stream);
    hipMemsetAsync(pcnt, 0, (size_t)N * 4, stream);
    hist_kernel<<<(E + 255) / 256, 256, 0, stream>>>(dst, cnt, E);
    int nb = (N + 1023) / 1024;
    scan_block<<<nb, 1024, 0, stream>>>(cnt, off, bsum, N);
    scan_tops<<<1, 256, 0, stream>>>(bsum, nb);
    scan_add<<<(N + 255) / 256, 256, 0, stream>>>(off, bsum, N, nb);
    scatter_kernel<<<(E + 255) / 256, 256, 0, stream>>>(src, dst, off, pcnt, csrc, E);

    int RB = (N + BM - 1) / BM;
    auto gemm = [&](const short* ah, const short* alo, const short* bth, const short* btl,
                    const float* bias, float* cf, short* chi, short* clo,
                    float* elp, float* erp, const float* alp, const float* arp,
                    int Nc, int flags) {
        dim3 grid((Nc + BN - 1) / BN, RB);
        gemm_mfma<<<grid, 256, 0, stream>>>(ah, alo, bth, btl, bias, cf, chi, clo,
                                            elp, erp, alp, arp, N, Nc, flags);
    };
    int nh_blocks = (N * 3 + 255) / 256;

    // ---- GAT layer 1
    gemm(P1h, P1l, w1th, w1tl, nullptr, nullptr, AbH, nullptr, el, er, al1, ar1, 384, 4 | 16);
    mden_kernel<<<nh_blocks, 256, 0, stream>>>(el, er, off, csrc, walpha, N);
    agg_kernel<<<N, 192, 0, stream>>>(AbH, walpha, off, csrc, b1, P2h, P2l, N);

    // ---- GAT layer 2
    gemm(P2h, P2l, w2th, w2tl, nullptr, nullptr, AbH, nullptr, el, er, al2, ar2, 384, 4 | 16);
    mden_kernel<<<nh_blocks, 256, 0, stream>>>(el, er, off, csrc, walpha, N);
    agg_kernel<<<N, 192, 0, stream>>>(AbH, walpha, off, csrc, b2, P1h, P1l, N);

    // ---- MLP head (fused lin1..lin5)
    mlp_fused<<<RB, 256, 0, stream>>>(P1h, P1l,
                                      l1th, l1tl, l2th, l2tl, l3th, l3tl,
                                      l4th, l4tl, l5th, l5tl,
                                      lb1, lb2, lb3, lb4, lb5, out, N);
}

// Round 9
// 592.090 us; speedup vs baseline: 1.4582x; 1.0886x over previous
//
#include <hip/hip_runtime.h>
#include <hip/hip_bf16.h>

// ---------------------------------------------------------------------------
// GAT (2 GATConv + 5-layer MLP), MI355X.
// R4 (proven): bf16 hi/lo planes end-to-end, split-bf16 MFMA (3 terms),
//     fused el/er in GEMM epilogue.
// R7 (proven): agg block-per-node, 192 threads = 3 heads x 64 lanes,
//     2 feats/lane uint loads. R8: mlp_fused (lin1..lin5 in one kernel).
// R9: edge softmax folded into agg's chunk loop (wave==head, online softmax,
//     wave-private LDS weight row); mden + walpha deleted; 1 memset.
// ---------------------------------------------------------------------------

typedef __attribute__((ext_vector_type(8))) short short8;   // 8 bf16 = 4 VGPR
typedef __attribute__((ext_vector_type(4))) float float4v;  // MFMA C/D

__device__ inline short f2bf(float x) {
    union { float f; unsigned u; } v; v.f = x;
    unsigned r = v.u + 0x7FFFu + ((v.u >> 16) & 1u);   // RNE
    return (short)(r >> 16);
}
__device__ inline float bf2f(short b) {
    union { float f; unsigned u; } v;
    v.u = ((unsigned)(unsigned short)b) << 16;
    return v.f;
}
__device__ inline short8 zero8() { short8 z = {0,0,0,0,0,0,0,0}; return z; }

#define BM 128
#define BN 128
#define BK 32
#define LSTR 40    // LDS row stride in shorts (80 B, 16B-aligned, breaks pow2)
#define MSTR 136   // act row stride in shorts (272 B = 17x16B, breaks pow2)

// ---------------------------------------------------------------------------
__global__ void conv_split(const float* __restrict__ x, short* __restrict__ hi,
                           short* __restrict__ lo, int n4)
{
    int i = blockIdx.x * blockDim.x + threadIdx.x;
    if (i >= n4) return;
    float4 v = *(const float4*)(x + (size_t)i * 4);
    float xs[4] = {v.x, v.y, v.z, v.w};
    short hs[4], ls[4];
    #pragma unroll
    for (int j = 0; j < 4; ++j) {
        hs[j] = f2bf(xs[j]);
        ls[j] = f2bf(xs[j] - bf2f(hs[j]));
    }
    *(uint2*)(hi + (size_t)i * 4) = *(uint2*)hs;
    *(uint2*)(lo + (size_t)i * 4) = *(uint2*)ls;
}

// All 7 weight matrices: fp32 [128][Nc] -> transposed bf16 hi/lo [Nc][128].
__global__ void convw_all(
    const float* __restrict__ w1, const float* __restrict__ w2,
    const float* __restrict__ m1, const float* __restrict__ m2,
    const float* __restrict__ m3, const float* __restrict__ m4,
    const float* __restrict__ w5,
    short* __restrict__ w1h, short* __restrict__ w1l,
    short* __restrict__ w2h, short* __restrict__ w2l,
    short* __restrict__ m1h, short* __restrict__ m1l,
    short* __restrict__ m2h, short* __restrict__ m2l,
    short* __restrict__ m3h, short* __restrict__ m3l,
    short* __restrict__ m4h, short* __restrict__ m4l,
    short* __restrict__ w5h, short* __restrict__ w5l)
{
    const float* src; short* th; short* tl; int Nc;
    switch (blockIdx.y) {
        case 0: src = w1; th = w1h; tl = w1l; Nc = 384; break;
        case 1: src = w2; th = w2h; tl = w2l; Nc = 384; break;
        case 2: src = m1; th = m1h; tl = m1l; Nc = 128; break;
        case 3: src = m2; th = m2h; tl = m2l; Nc = 128; break;
        case 4: src = m3; th = m3h; tl = m3l; Nc = 128; break;
        case 5: src = m4; th = m4h; tl = m4l; Nc = 128; break;
        default: src = w5; th = w5h; tl = w5l; Nc = 6; break;
    }
    int i = blockIdx.x * blockDim.x + threadIdx.x;
    if (i >= 128 * Nc) return;
    int k = i / Nc, c = i - k * Nc;
    float v = src[i];
    short h = f2bf(v);
    th[(size_t)c * 128 + k] = h;
    tl[(size_t)c * 128 + k] = f2bf(v - bf2f(h));
}

// ---------------------------------------------------------------------------
// GEMM (GAT layers): C[M x Nc] = A @ W, fused el/er. flags as before.
__global__ __launch_bounds__(256) void gemm_mfma(
    const short* __restrict__ Ahi, const short* __restrict__ Alo,
    const short* __restrict__ Bth, const short* __restrict__ Btl,
    const float* __restrict__ bias,
    float* __restrict__ Cf, short* __restrict__ Chi, short* __restrict__ Clo,
    float* __restrict__ el, float* __restrict__ er,
    const float* __restrict__ al, const float* __restrict__ ar,
    int M, int Nc, int flags)
{
    __shared__ short Ah[BM * LSTR], Al_[BM * LSTR];
    __shared__ short Bh[BN * LSTR], Bl_[BN * LSTR];

    int tid = threadIdx.x, lane = tid & 63, wave = tid >> 6;
    int l15 = lane & 15, q = lane >> 4;
    int rowBase = blockIdx.y * BM, colBase = blockIdx.x * BN;

    float4v acc[2][8];
    #pragma unroll
    for (int mt = 0; mt < 2; ++mt)
        #pragma unroll
        for (int nt = 0; nt < 8; ++nt)
            acc[mt][nt] = (float4v){0.f, 0.f, 0.f, 0.f};

    for (int k0 = 0; k0 < 128; k0 += BK) {
        #pragma unroll
        for (int s = 0; s < 2; ++s) {
            int c = tid + s * 256;
            int r = c >> 2, kq = (c & 3) * 8;
            int gr = rowBase + r;
            short8 vh = zero8(), vl = zero8();
            if (gr < M) {
                vh = *(const short8*)(Ahi + (size_t)gr * 128 + k0 + kq);
                vl = *(const short8*)(Alo + (size_t)gr * 128 + k0 + kq);
            }
            *(short8*)&Ah[r * LSTR + kq]  = vh;
            *(short8*)&Al_[r * LSTR + kq] = vl;
            int gc = colBase + r;
            short8 wh = zero8(), wl = zero8();
            if (gc < Nc) {
                wh = *(const short8*)(Bth + (size_t)gc * 128 + k0 + kq);
                wl = *(const short8*)(Btl + (size_t)gc * 128 + k0 + kq);
            }
            *(short8*)&Bh[r * LSTR + kq]  = wh;
            *(short8*)&Bl_[r * LSTR + kq] = wl;
        }
        __syncthreads();

        short8 aH[2], aL2[2];
        #pragma unroll
        for (int mt = 0; mt < 2; ++mt) {
            int off = (wave * 32 + mt * 16 + l15) * LSTR + q * 8;
            aH[mt]  = *(short8*)&Ah[off];
            aL2[mt] = *(short8*)&Al_[off];
        }
        #pragma unroll
        for (int nt = 0; nt < 8; ++nt) {
            int off = (nt * 16 + l15) * LSTR + q * 8;
            short8 bH = *(short8*)&Bh[off];
            short8 bL = *(short8*)&Bl_[off];
            #pragma unroll
            for (int mt = 0; mt < 2; ++mt) {
                acc[mt][nt] = __builtin_amdgcn_mfma_f32_16x16x32_bf16(aH[mt], bH, acc[mt][nt], 0, 0, 0);
                acc[mt][nt] = __builtin_amdgcn_mfma_f32_16x16x32_bf16(aH[mt], bL, acc[mt][nt], 0, 0, 0);
                acc[mt][nt] = __builtin_amdgcn_mfma_f32_16x16x32_bf16(aL2[mt], bH, acc[mt][nt], 0, 0, 0);
            }
        }
        __syncthreads();
    }

    if (flags & 4) {
        const float* alh = al + colBase;
        const float* arh = ar + colBase;
        float pel[2][4] = {}, per_[2][4] = {};
        #pragma unroll
        for (int nt = 0; nt < 8; ++nt) {
            float av = alh[nt * 16 + l15];
            float rv = arh[nt * 16 + l15];
            #pragma unroll
            for (int mt = 0; mt < 2; ++mt)
                #pragma unroll
                for (int i = 0; i < 4; ++i) {
                    pel[mt][i]  += acc[mt][nt][i] * av;
                    per_[mt][i] += acc[mt][nt][i] * rv;
                }
        }
        #pragma unroll
        for (int mask = 1; mask < 16; mask <<= 1)
            #pragma unroll
            for (int mt = 0; mt < 2; ++mt)
                #pragma unroll
                for (int i = 0; i < 4; ++i) {
                    pel[mt][i]  += __shfl_xor(pel[mt][i], mask);
                    per_[mt][i] += __shfl_xor(per_[mt][i], mask);
                }
        if (l15 == 0) {
            #pragma unroll
            for (int mt = 0; mt < 2; ++mt)
                #pragma unroll
                for (int i = 0; i < 4; ++i) {
                    int r = rowBase + wave * 32 + mt * 16 + q * 4 + i;
                    if (r < M) {
                        el[r * 3 + blockIdx.x] = pel[mt][i];
                        er[r * 3 + blockIdx.x] = per_[mt][i];
                    }
                }
        }
    }

    #pragma unroll
    for (int mt = 0; mt < 2; ++mt) {
        #pragma unroll
        for (int nt = 0; nt < 8; ++nt) {
            int c = colBase + nt * 16 + l15;
            if (c >= Nc) continue;
            float bv = (flags & 1) ? bias[c] : 0.f;
            #pragma unroll
            for (int i = 0; i < 4; ++i) {
                int r = rowBase + wave * 32 + mt * 16 + q * 4 + i;
                if (r >= M) continue;
                float v = acc[mt][nt][i] + bv;
                if (flags & 2) v = (v < 0.f) ? 0.01f * v : v;
                size_t idx = (size_t)r * Nc + c;
                if (flags & 8)  Cf[idx] = v;
                if (flags & 16) {
                    short hh = f2bf(v);
                    Chi[idx] = hh;
                    if (flags & 32) Clo[idx] = f2bf(v - bf2f(hh));
                }
            }
        }
    }
}

// ---------------------------------------------------------------------------
// Fused MLP head: 4x (128->128, bias, lrelu) + (128->6, bias) in one kernel.
__global__ __launch_bounds__(256) void mlp_fused(
    const short* __restrict__ Ph, const short* __restrict__ Pl,
    const short* __restrict__ w1h, const short* __restrict__ w1l,
    const short* __restrict__ w2h, const short* __restrict__ w2l,
    const short* __restrict__ w3h, const short* __restrict__ w3l,
    const short* __restrict__ w4h, const short* __restrict__ w4l,
    const short* __restrict__ w5h, const short* __restrict__ w5l,
    const float* __restrict__ b1, const float* __restrict__ b2,
    const float* __restrict__ b3, const float* __restrict__ b4,
    const float* __restrict__ b5,
    float* __restrict__ out, int M)
{
    __shared__ short AH[128 * MSTR], AL[128 * MSTR];   // activations hi/lo
    __shared__ short WH[128 * LSTR], WL[128 * LSTR];   // weight BK-chunk

    int tid = threadIdx.x, lane = tid & 63, wave = tid >> 6;
    int l15 = lane & 15, q = lane >> 4;
    int rowBase = blockIdx.x * 128;

    #pragma unroll
    for (int s = 0; s < 8; ++s) {
        int idx = tid + s * 256;
        int r = idx >> 4, kq = (idx & 15) * 8;
        int gr = rowBase + r;
        short8 vh = zero8(), vl = zero8();
        if (gr < M) {
            vh = *(const short8*)(Ph + (size_t)gr * 128 + kq);
            vl = *(const short8*)(Pl + (size_t)gr * 128 + kq);
        }
        *(short8*)&AH[r * MSTR + kq] = vh;
        *(short8*)&AL[r * MSTR + kq] = vl;
    }

    const short* Whs[4] = {w1h, w2h, w3h, w4h};
    const short* Wls[4] = {w1l, w2l, w3l, w4l};
    const float* Bss[4] = {b1, b2, b3, b4};

    #pragma unroll
    for (int L = 0; L < 4; ++L) {
        float4v acc[2][8];
        #pragma unroll
        for (int mt = 0; mt < 2; ++mt)
            #pragma unroll
            for (int nt = 0; nt < 8; ++nt)
                acc[mt][nt] = (float4v){0.f, 0.f, 0.f, 0.f};

        for (int k0 = 0; k0 < 128; k0 += BK) {
            #pragma unroll
            for (int s = 0; s < 4; ++s) {
                int idx = tid + s * 256;
                int plane = idx >> 9, rem = idx & 511;
                int c = rem >> 2, kq = (rem & 3) * 8;
                short8 v = *(const short8*)((plane ? Wls[L] : Whs[L]) +
                                            (size_t)c * 128 + k0 + kq);
                *(short8*)&((plane ? WL : WH)[c * LSTR + kq]) = v;
            }
            __syncthreads();
            short8 aH[2], aL2[2];
            #pragma unroll
            for (int mt = 0; mt < 2; ++mt) {
                int off = (wave * 32 + mt * 16 + l15) * MSTR + k0 + q * 8;
                aH[mt]  = *(short8*)&AH[off];
                aL2[mt] = *(short8*)&AL[off];
            }
            #pragma unroll
            for (int nt = 0; nt < 8; ++nt) {
                int off = (nt * 16 + l15) * LSTR + q * 8;
                short8 bH = *(short8*)&WH[off];
                short8 bL = *(short8*)&WL[off];
                #pragma unroll
                for (int mt = 0; mt < 2; ++mt) {
                    acc[mt][nt] = __builtin_amdgcn_mfma_f32_16x16x32_bf16(aH[mt], bH, acc[mt][nt], 0, 0, 0);
                    acc[mt][nt] = __builtin_amdgcn_mfma_f32_16x16x32_bf16(aH[mt], bL, acc[mt][nt], 0, 0, 0);
                    acc[mt][nt] = __builtin_amdgcn_mfma_f32_16x16x32_bf16(aL2[mt], bH, acc[mt][nt], 0, 0, 0);
                }
            }
            __syncthreads();
        }
        #pragma unroll
        for (int mt = 0; mt < 2; ++mt) {
            #pragma unroll
            for (int nt = 0; nt < 8; ++nt) {
                int c = nt * 16 + l15;
                float bv = Bss[L][c];
                #pragma unroll
                for (int i = 0; i < 4; ++i) {
                    int r = wave * 32 + mt * 16 + q * 4 + i;
                    float v = acc[mt][nt][i] + bv;
                    v = (v < 0.f) ? 0.01f * v : v;
                    short hh = f2bf(v);
                    AH[r * MSTR + c] = hh;
                    AL[r * MSTR + c] = f2bf(v - bf2f(hh));
                }
            }
        }
        __syncthreads();
    }

    float4v acc5[2];
    acc5[0] = (float4v){0.f, 0.f, 0.f, 0.f};
    acc5[1] = (float4v){0.f, 0.f, 0.f, 0.f};
    for (int k0 = 0; k0 < 128; k0 += BK) {
        if (tid < 128) {
            int plane = tid >> 6, rem = tid & 63;
            int c = rem >> 2, kq = (rem & 3) * 8;
            short8 v = zero8();
            if (c < 6)
                v = *(const short8*)((plane ? w5l : w5h) + (size_t)c * 128 + k0 + kq);
            *(short8*)&((plane ? WL : WH)[c * LSTR + kq]) = v;
        }
        __syncthreads();
        short8 aH[2], aL2[2];
        #pragma unroll
        for (int mt = 0; mt < 2; ++mt) {
            int off = (wave * 32 + mt * 16 + l15) * MSTR + k0 + q * 8;
            aH[mt]  = *(short8*)&AH[off];
            aL2[mt] = *(short8*)&AL[off];
        }
        int offb = l15 * LSTR + q * 8;
        short8 bH = *(short8*)&WH[offb];
        short8 bL = *(short8*)&WL[offb];
        #pragma unroll
        for (int mt = 0; mt < 2; ++mt) {
            acc5[mt] = __builtin_amdgcn_mfma_f32_16x16x32_bf16(aH[mt], bH, acc5[mt], 0, 0, 0);
            acc5[mt] = __builtin_amdgcn_mfma_f32_16x16x32_bf16(aH[mt], bL, acc5[mt], 0, 0, 0);
            acc5[mt] = __builtin_amdgcn_mfma_f32_16x16x32_bf16(aL2[mt], bH, acc5[mt], 0, 0, 0);
        }
        __syncthreads();
    }
    if (l15 < 6) {
        float bv = b5[l15];
        #pragma unroll
        for (int mt = 0; mt < 2; ++mt)
            #pragma unroll
            for (int i = 0; i < 4; ++i) {
                int r = rowBase + wave * 32 + mt * 16 + q * 4 + i;
                if (r < M) out[(size_t)r * 6 + l15] = acc5[mt][i] + bv;
            }
    }
}

// ---------------------------------------------------------------------------
// CSR build
__global__ void hist_kernel(const int* __restrict__ dst, int* __restrict__ cnt, int E)
{
    int e = blockIdx.x * blockDim.x + threadIdx.x;
    if (e < E) atomicAdd(&cnt[dst[e]], 1);
}

__global__ __launch_bounds__(1024) void scan_block(const int* __restrict__ cnt,
                                                   int* __restrict__ off,
                                                   int* __restrict__ bsum, int n)
{
    __shared__ int tmp[1024];
    int tid = threadIdx.x;
    int i = blockIdx.x * 1024 + tid;
    int v = (i < n) ? cnt[i] : 0;
    tmp[tid] = v;
    __syncthreads();
    for (int s = 1; s < 1024; s <<= 1) {
        int t = (tid >= s) ? tmp[tid - s] : 0;
        __syncthreads();
        tmp[tid] += t;
        __syncthreads();
    }
    if (i < n) off[i] = tmp[tid] - v;
    if (tid == 1023) bsum[blockIdx.x] = tmp[1023];
}

__global__ __launch_bounds__(256) void scan_tops(int* __restrict__ bsum, int nb)
{
    __shared__ int tmp[256];
    int tid = threadIdx.x;
    int v = (tid < nb) ? bsum[tid] : 0;
    tmp[tid] = v;
    __syncthreads();
    for (int s = 1; s < 256; s <<= 1) {
        int t = (tid >= s) ? tmp[tid - s] : 0;
        __syncthreads();
        tmp[tid] += t;
        __syncthreads();
    }
    if (tid < nb) bsum[tid] = tmp[tid] - v;
    if (tid == 0) bsum[nb] = tmp[255];
}

__global__ void scan_add(int* __restrict__ off, const int* __restrict__ bsum,
                         int n, int nb)
{
    int i = blockIdx.x * blockDim.x + threadIdx.x;
    if (i < n) off[i] += bsum[i >> 10];
    if (i == 0) off[n] = bsum[nb];
}

__global__ void scatter_kernel(const int* __restrict__ src, const int* __restrict__ dst,
                               const int* __restrict__ off, int* __restrict__ pcnt,
                               int* __restrict__ csrc, int E)
{
    int e = blockIdx.x * blockDim.x + threadIdx.x;
    if (e < E) {
        int d = dst[e];
        int p = atomicAdd(&pcnt[d], 1);
        csrc[off[d] + p] = src[e];
    }
}

// ---------------------------------------------------------------------------
// Fused edge-softmax + weighted gather + bias + lrelu + head-mean.
// Block per node, 192 threads = 3 waves; wave w == head w, lane l owns
// feature pair (2l, 2l+1). Per 64-edge chunk: wave computes e lane-parallel,
// shfl max/sum with online-softmax rescale, weights in wave-private LDS row,
// then R7's edge-parallel gather. Divide by den at the end.
__global__ __launch_bounds__(192) void agg_kernel(
    const short* __restrict__ h, const float* __restrict__ el,
    const float* __restrict__ er, const int* __restrict__ off,
    const int* __restrict__ csrc, const float* __restrict__ bias,
    short* __restrict__ outH, short* __restrict__ outL, int N)
{
    int n = blockIdx.x;
    int tid = threadIdx.x;         // 0..191
    int head = tid >> 6;           // 0..2 == wave index
    int l = tid & 63;
    int beg = off[n], end = off[n + 1];
    int deg = end - beg;

    __shared__ int   ssrc[64];
    __shared__ float sw[3][64];    // wave-private rows
    __shared__ float sm[384];

    int fbase = head * 128 + 2 * l;
    float erv = er[n * 3 + head];
    float ax = 0.f, ay = 0.f, den = 0.f, m_run = -1e30f;

    for (int base = 0; base < deg; base += 64) {
        int cnt = min(64, deg - base);
        if (tid < cnt) ssrc[tid] = csrc[beg + base + tid];
        __syncthreads();
        // --- per-wave softmax over this chunk (online across chunks)
        float e = -1e30f;
        if (l < cnt) {
            float t = el[ssrc[l] * 3 + head] + erv;
            e = (t < 0.f) ? 0.2f * t : t;
        }
        float mc = e;
        #pragma unroll
        for (int msk = 1; msk < 64; msk <<= 1) mc = fmaxf(mc, __shfl_xor(mc, msk));
        float m_new = fmaxf(m_run, mc);
        float scale = __expf(m_run - m_new);   // first chunk: exp(-inf)=0, accs are 0
        ax *= scale; ay *= scale; den *= scale;
        float w = (l < cnt) ? __expf(e - m_new) : 0.f;
        float wsum = w;
        #pragma unroll
        for (int msk = 1; msk < 64; msk <<= 1) wsum += __shfl_xor(wsum, msk);
        den += wsum;
        sw[head][l] = w;           // same-wave write->read: no barrier needed
        m_run = m_new;
        // --- edge-parallel gather (R7-proven)
        #pragma unroll 4
        for (int qq = 0; qq < cnt; ++qq) {
            int s = ssrc[qq];
            float w2 = sw[head][qq];
            unsigned v = *(const unsigned*)(h + (size_t)s * 384 + fbase);
            union { unsigned u; float f; } f0, f1;
            f0.u = v << 16; f1.u = v & 0xffff0000u;
            ax += w2 * f0.f;
            ay += w2 * f1.f;
        }
        __syncthreads();           // protect ssrc/sw reuse next chunk
    }
    float r = 1.f / (den + 1e-9f);   // deg==0: ax=ay=0, result 0 + bias
    if (deg == 0) r = 0.f;
    float2 bv = *(const float2*)(bias + fbase);
    float vx = ax * r + bv.x; vx = (vx < 0.f) ? 0.01f * vx : vx;
    float vy = ay * r + bv.y; vy = (vy < 0.f) ? 0.01f * vy : vy;
    sm[fbase]     = vx;
    sm[fbase + 1] = vy;
    __syncthreads();
    if (tid < 64) {
        int f0i = tid * 2, f1i = f0i + 1;
        float mx = (sm[f0i] + sm[128 + f0i] + sm[256 + f0i]) * (1.0f / 3.0f);
        float my = (sm[f1i] + sm[128 + f1i] + sm[256 + f1i]) * (1.0f / 3.0f);
        short hx = f2bf(mx), lx = f2bf(mx - bf2f(hx));
        short hy = f2bf(my), ly = f2bf(my - bf2f(hy));
        unsigned ph = (unsigned)(unsigned short)hx | ((unsigned)(unsigned short)hy << 16);
        unsigned pl = (unsigned)(unsigned short)lx | ((unsigned)(unsigned short)ly << 16);
        *(unsigned*)(outH + (size_t)n * 128 + f0i) = ph;
        *(unsigned*)(outL + (size_t)n * 128 + f0i) = pl;
    }
}

// ---------------------------------------------------------------------------
extern "C" void kernel_launch(void* const* d_in, const int* in_sizes, int n_in,
                              void* d_out, int out_size, void* d_ws, size_t ws_size,
                              hipStream_t stream)
{
    const float* in_feat = (const float*)d_in[0];
    const int*   src     = (const int*)d_in[1];
    const int*   dst     = (const int*)d_in[2];
    const float* W1  = (const float*)d_in[3];
    const float* al1 = (const float*)d_in[4];
    const float* ar1 = (const float*)d_in[5];
    const float* b1  = (const float*)d_in[6];
    const float* W2  = (const float*)d_in[7];
    const float* al2 = (const float*)d_in[8];
    const float* ar2 = (const float*)d_in[9];
    const float* b2  = (const float*)d_in[10];
    const float* lw1 = (const float*)d_in[11];
    const float* lb1 = (const float*)d_in[12];
    const float* lw2 = (const float*)d_in[13];
    const float* lb2 = (const float*)d_in[14];
    const float* lw3 = (const float*)d_in[15];
    const float* lb3 = (const float*)d_in[16];
    const float* lw4 = (const float*)d_in[17];
    const float* lb4 = (const float*)d_in[18];
    const float* lw5 = (const float*)d_in[19];
    const float* lb5 = (const float*)d_in[20];

    const int N = in_sizes[0] / 128;   // 50000
    const int E = in_sizes[1];         // 800000

    size_t o = 0;
    auto alloc = [&](size_t bytes) { size_t p = o; o = (o + bytes + 255) & ~(size_t)255; return p; };
    char* ws = (char*)d_ws;
    short* P1h = (short*)(ws + alloc((size_t)N * 128 * 2));
    short* P1l = (short*)(ws + alloc((size_t)N * 128 * 2));
    short* P2h = (short*)(ws + alloc((size_t)N * 128 * 2));
    short* P2l = (short*)(ws + alloc((size_t)N * 128 * 2));
    short* AbH = (short*)(ws + alloc((size_t)N * 384 * 2));   // GAT gemm out, hi, node-major
    float* el  = (float*)(ws + alloc((size_t)N * 3 * 4));
    float* er  = (float*)(ws + alloc((size_t)N * 3 * 4));
    int*   cnt  = (int*)(ws + alloc((size_t)2 * N * 4));      // cnt[N] + pcnt[N], one memset
    int*   pcnt = cnt + N;
    int*   off  = (int*)(ws + alloc((size_t)(N + 1) * 4));
    int*   bsum = (int*)(ws + alloc((size_t)4096));
    int*   csrc = (int*)(ws + alloc((size_t)E * 4));
    short* w1th = (short*)(ws + alloc((size_t)384 * 128 * 2));
    short* w1tl = (short*)(ws + alloc((size_t)384 * 128 * 2));
    short* w2th = (short*)(ws + alloc((size_t)384 * 128 * 2));
    short* w2tl = (short*)(ws + alloc((size_t)384 * 128 * 2));
    short* l1th = (short*)(ws + alloc((size_t)128 * 128 * 2));
    short* l1tl = (short*)(ws + alloc((size_t)128 * 128 * 2));
    short* l2th = (short*)(ws + alloc((size_t)128 * 128 * 2));
    short* l2tl = (short*)(ws + alloc((size_t)128 * 128 * 2));
    short* l3th = (short*)(ws + alloc((size_t)128 * 128 * 2));
    short* l3tl = (short*)(ws + alloc((size_t)128 * 128 * 2));
    short* l4th = (short*)(ws + alloc((size_t)128 * 128 * 2));
    short* l4tl = (short*)(ws + alloc((size_t)128 * 128 * 2));
    short* l5th = (short*)(ws + alloc((size_t)6 * 128 * 2));
    short* l5tl = (short*)(ws + alloc((size_t)6 * 128 * 2));
    (void)ws_size;

    float* out = (float*)d_out;

    // ---- input/weight conversions
    conv_split<<<(N * 128 / 4 + 255) / 256, 256, 0, stream>>>(in_feat, P1h, P1l, N * 128 / 4);
    {
        dim3 grid((128 * 384 + 255) / 256, 7);
        convw_all<<<grid, 256, 0, stream>>>(W1, W2, lw1, lw2, lw3, lw4, lw5,
                                            w1th, w1tl, w2th, w2tl,
                                            l1th, l1tl, l2th, l2tl,
                                            l3th, l3tl, l4th, l4tl,
                                            l5th, l5tl);
    }

    // ---- CSR build
    hipMemsetAsync(cnt, 0, (size_t)2 * N * 4, stream);
    hist_kernel<<<(E + 255) / 256, 256, 0, stream>>>(dst, cnt, E);
    int nb = (N + 1023) / 1024;
    scan_block<<<nb, 1024, 0, stream>>>(cnt, off, bsum, N);
    scan_tops<<<1, 256, 0, stream>>>(bsum, nb);
    scan_add<<<(N + 255) / 256, 256, 0, stream>>>(off, bsum, N, nb);
    scatter_kernel<<<(E + 255) / 256, 256, 0, stream>>>(src, dst, off, pcnt, csrc, E);

    int RB = (N + BM - 1) / BM;
    auto gemm = [&](const short* ah, const short* alo, const short* bth, const short* btl,
                    const float* bias, float* cf, short* chi, short* clo,
                    float* elp, float* erp, const float* alp, const float* arp,
                    int Nc, int flags) {
        dim3 grid((Nc + BN - 1) / BN, RB);
        gemm_mfma<<<grid, 256, 0, stream>>>(ah, alo, bth, btl, bias, cf, chi, clo,
                                            elp, erp, alp, arp, N, Nc, flags);
    };

    // ---- GAT layer 1
    gemm(P1h, P1l, w1th, w1tl, nullptr, nullptr, AbH, nullptr, el, er, al1, ar1, 384, 4 | 16);
    agg_kernel<<<N, 192, 0, stream>>>(AbH, el, er, off, csrc, b1, P2h, P2l, N);

    // ---- GAT layer 2
    gemm(P2h, P2l, w2th, w2tl, nullptr, nullptr, AbH, nullptr, el, er, al2, ar2, 384, 4 | 16);
    agg_kernel<<<N, 192, 0, stream>>>(AbH, el, er, off, csrc, b2, P1h, P1l, N);

    // ---- MLP head (fused lin1..lin5)
    mlp_fused<<<RB, 256, 0, stream>>>(P1h, P1l,
                                      l1th, l1tl, l2th, l2tl, l3th, l3tl,
                                      l4th, l4tl, l5th, l5tl,
                                      lb1, lb2, lb3, lb4, lb5, out, N);
}